// Round 22
// baseline (121.674 us; speedup 1.0000x reference)
//
#include <hip/hip_runtime.h>
#include <hip/hip_bf16.h>

// MultiheadAttention: out = (softmax_causal((Xq Wq^T)(Xk Wk^T)^T / 8) (Xv Wv^T)) Wo^T
// B=2 S=2048 D=1024 H=16 dk=64. bf16 MFMA (16x16x32), fp32 accum.
// R22: proj_qkv widened to 16 waves (1024 thr, 4x4 wave grid, 64x64 wave
//      tile): 4 waves/SIMD (was 2) -> more independent streams per phase
//      region. Staging = 1 gload/thread/half-tile; drains vmcnt(3)/(2).
//      flash/proj_out/cvt byte-identical to R21.

typedef __attribute__((ext_vector_type(8))) __bf16 bf16x8;
typedef __attribute__((ext_vector_type(4))) __bf16 bf16x4;
typedef __attribute__((ext_vector_type(4))) float f32x4;

#define MFMA16(a, b, c) __builtin_amdgcn_mfma_f32_16x16x32_bf16((a), (b), (c), 0, 0, 0)

constexpr int D_MODEL = 1024;
constexpr int HEADS   = 16;
constexpr int DKH     = 64;
constexpr int BATCH   = 2;
constexpr int SEQ     = 2048;
constexpr int M_ROWS  = BATCH * SEQ;  // 4096
constexpr int QB = 64, KB = 64, NT = SEQ / QB;  // 32 q-tiles

typedef const unsigned int __attribute__((address_space(1)))* gas_u32;
typedef unsigned int __attribute__((address_space(3)))* las_u32;

// ---------------------------------------------------------------------------
// fp32 -> bf16 convert; seg 3 (Wq) pre-scaled by 0.125*log2(e) (exp2 softmax).
// Segs 0-5 granule-swizzled for the 8-phase GEMM staging (rule #21).
// ---------------------------------------------------------------------------
struct CvtArgs {
  const float* src[7];
  __bf16* dst[7];
  int n8[7];
};

__global__ __launch_bounds__(256) void cvt_bf16(CvtArgs a) {
  const int z = blockIdx.z;
  const int i = blockIdx.x * 256 + threadIdx.x;
  if (i >= a.n8[z]) return;
  const float sc = (z == 3) ? 0.18033688011112042f : 1.0f;  // 0.125*log2e
  const float4* s = (const float4*)a.src[z] + (size_t)i * 2;
  float4 x = s[0], y = s[1];
  bf16x8 o = {(__bf16)(x.x * sc), (__bf16)(x.y * sc), (__bf16)(x.z * sc), (__bf16)(x.w * sc),
              (__bf16)(y.x * sc), (__bf16)(y.y * sc), (__bf16)(y.z * sc), (__bf16)(y.w * sc)};
  size_t oi = (size_t)i;
  if (z < 6) {
    const int row = i >> 7;  // 1024 elems = 128 granules per row
    oi = (size_t)((i & ~7) | ((i & 7) ^ (row & 7)));
  }
  *(bf16x8*)(a.dst[z] + oi * 8) = o;
}

// ---------------------------------------------------------------------------
// 8-phase 256x256 GEMM, 16 waves (4x4 grid, 64x64 wave tile). Staging:
// half-tile (128x64) = 1024 granules = 1 gload/thread. Drain audit:
// prologue 6 stages -> vmcnt(2); steady vmcnt(3)@P4, vmcnt(2)@P8 (each
// retires exactly the consumed tile's 4 stages); last iter vmcnt(0)@P4.
// ---------------------------------------------------------------------------
__global__ __launch_bounds__(1024, 1) void proj_qkv(
    const __bf16* __restrict__ Xq, const __bf16* __restrict__ Xk,
    const __bf16* __restrict__ Xv, const __bf16* __restrict__ Wq,
    const __bf16* __restrict__ Wk, const __bf16* __restrict__ Wv,
    __bf16* __restrict__ Q, __bf16* __restrict__ K, __bf16* __restrict__ Vt) {
  __shared__ alignas(16) __bf16 As[2 * 256 * 64];  // 64 KB
  __shared__ alignas(16) __bf16 Bs[2 * 256 * 64];  // 64 KB

  int f = (blockIdx.z * gridDim.y + blockIdx.y) * gridDim.x + blockIdx.x;
  f = (f & 7) * 24 + (f >> 3);
  const int bx = f & 3, by = (f >> 2) & 15, bz = f >> 6;

  const __bf16* Ag; const __bf16* Bg;
  if (bz == 0)      { Ag = Xq; Bg = Wq; }
  else if (bz == 1) { Ag = Xk; Bg = Wk; }
  else              { Ag = Xv; Bg = Wv; }

  const int bm = by * 256, bn = bx * 256;
  const int tid = threadIdx.x, ln = tid & 63, wv = tid >> 6;  // wv 0..15
  const int wr = wv >> 2, wc = wv & 3;       // 4x4 wave grid, 64x64 tile
  const int fr = ln & 15, fg = ln >> 4;

  // one half-tile (128 rows x 64 cols) = 1024 granules; granule d = wv*64+ln
  auto stageA = [&](int buf, int h, int t) {
    const int d = wv * 64 + ln;
    const __bf16* src = Ag + (size_t)(bm + h * 128 + (d >> 3)) * 1024 + t * 64 + (d & 7) * 8;
    __builtin_amdgcn_global_load_lds((gas_u32)src,
        (las_u32)(As + (size_t)(buf * 2048 + h * 1024 + wv * 64) * 8), 16, 0, 0);
  };
  auto stageB = [&](int buf, int h, int t) {
    const int d = wv * 64 + ln;
    const __bf16* src = Bg + (size_t)(bn + h * 128 + (d >> 3)) * 1024 + t * 64 + (d & 7) * 8;
    __builtin_amdgcn_global_load_lds((gas_u32)src,
        (las_u32)(Bs + (size_t)(buf * 2048 + h * 1024 + wv * 64) * 8), 16, 0, 0);
  };

  f32x4 acc[4][4];
#pragma unroll
  for (int m = 0; m < 4; ++m)
#pragma unroll
    for (int n = 0; n < 4; ++n) acc[m][n] = (f32x4){0.f, 0.f, 0.f, 0.f};

  bf16x8 ra[2][2], rb[4][2];

  auto loadA = [&](int buf, int mbase) {  // fills ra[0..1] for m = mbase..+1
#pragma unroll
    for (int m = 0; m < 2; ++m)
#pragma unroll
      for (int kk = 0; kk < 2; ++kk) {
        const int row = wr * 64 + (mbase + m) * 16 + fr;
        ra[m][kk] = *(const bf16x8*)&As[(buf * 256 + row) * 64 +
                                        (((kk * 4 + fg) ^ (row & 7)) << 3)];
      }
  };
  auto loadB = [&](int buf, int n0) {  // fills rb[n0..n0+1]
#pragma unroll
    for (int n = 0; n < 2; ++n)
#pragma unroll
      for (int kk = 0; kk < 2; ++kk) {
        const int row = wc * 64 + (n0 + n) * 16 + fr;
        rb[n0 + n][kk] = *(const bf16x8*)&Bs[(buf * 256 + row) * 64 +
                                             (((kk * 4 + fg) ^ (row & 7)) << 3)];
      }
  };
  auto quad = [&](int macc, int nb) {  // 8 MFMA: 2m x 2n x 2kk
    __builtin_amdgcn_s_setprio(1);
#pragma unroll
    for (int m = 0; m < 2; ++m)
#pragma unroll
      for (int n = 0; n < 2; ++n) {
        acc[macc + m][nb + n] = MFMA16(ra[m][0], rb[nb + n][0], acc[macc + m][nb + n]);
        acc[macc + m][nb + n] = MFMA16(ra[m][1], rb[nb + n][1], acc[macc + m][nb + n]);
      }
    __builtin_amdgcn_s_setprio(0);
  };

  // prologue: tile0 (4 halves) + Bh0/Ah0 of tile1 = 6 stages; drain tile0
  stageB(0, 0, 0); stageB(0, 1, 0); stageA(0, 0, 0); stageA(0, 1, 0);
  stageB(1, 0, 1); stageA(1, 0, 1);
  asm volatile("s_waitcnt vmcnt(2)" ::: "memory");
  __builtin_amdgcn_s_barrier();

#pragma unroll 1
  for (int it = 0; it < 8; ++it) {
    const int T0 = 2 * it, T1 = 2 * it + 1;
    const bool nl = (it < 7);

    // P1: A m0..1 + all B frags (buf0); stage Bh1(T1)
    loadA(0, 0); loadB(0, 0); loadB(0, 2);
    stageB(1, 1, T1);
    __builtin_amdgcn_s_barrier();
    quad(0, 0);
    __builtin_amdgcn_s_barrier();

    // P2: stage Ah1(T1) + Bh0(T0+2)
    stageA(1, 1, T1);
    if (nl) stageB(0, 0, T0 + 2);
    __builtin_amdgcn_s_barrier();
    quad(0, 2);
    __builtin_amdgcn_s_barrier();

    // P3: A m2..3; stage Bh1(T0+2)
    loadA(0, 2);
    if (nl) stageB(0, 1, T0 + 2);
    __builtin_amdgcn_s_barrier();
    quad(2, 0);
    __builtin_amdgcn_s_barrier();

    // P4: stage Ah0(T0+2); drain -> tile T1 fully landed
    if (nl) {
      stageA(0, 0, T0 + 2);
      asm volatile("s_waitcnt vmcnt(3)" ::: "memory");
    } else {
      asm volatile("s_waitcnt vmcnt(0)" ::: "memory");
    }
    __builtin_amdgcn_s_barrier();
    quad(2, 2);
    __builtin_amdgcn_s_barrier();

    // P5: A m0..1 + all B frags (buf1); stage Ah1(T0+2)
    loadA(1, 0); loadB(1, 0); loadB(1, 2);
    if (nl) stageA(0, 1, T0 + 2);
    __builtin_amdgcn_s_barrier();
    quad(0, 0);
    __builtin_amdgcn_s_barrier();

    // P6: stage Bh0(T1+2)
    if (nl) stageB(1, 0, T1 + 2);
    __builtin_amdgcn_s_barrier();
    quad(0, 2);
    __builtin_amdgcn_s_barrier();

    // P7: A m2..3
    loadA(1, 2);
    __builtin_amdgcn_s_barrier();
    quad(2, 0);
    __builtin_amdgcn_s_barrier();

    // P8: stage Ah0(T1+2); drain -> tile T0+2 fully landed
    if (nl) {
      stageA(1, 0, T1 + 2);
      asm volatile("s_waitcnt vmcnt(2)" ::: "memory");
    }
    __builtin_amdgcn_s_barrier();
    quad(2, 2);
    __builtin_amdgcn_s_barrier();
  }

  if (bz == 2) {
    const int b = bm >> 11;
#pragma unroll
    for (int m = 0; m < 4; ++m)
#pragma unroll
      for (int n = 0; n < 4; ++n) {
        const int col = bn + wc * 64 + n * 16 + fr;
        const int s0  = (bm + wr * 64 + m * 16 + fg * 4) & (SEQ - 1);
        bf16x4 o = {(__bf16)acc[m][n][0], (__bf16)acc[m][n][1],
                    (__bf16)acc[m][n][2], (__bf16)acc[m][n][3]};
        *(bf16x4*)(Vt + (((size_t)(b * 1024 + col)) << 11) + s0) = o;
      }
  } else {
    __bf16* C = (bz == 0) ? Q : K;
#pragma unroll
    for (int m = 0; m < 4; ++m)
#pragma unroll
      for (int n = 0; n < 4; ++n)
#pragma unroll
        for (int r = 0; r < 4; ++r) {
          const int row = bm + wr * 64 + m * 16 + fg * 4 + r;
          const int col = bn + wc * 64 + n * 16 + fr;
          C[(size_t)row * 1024 + col] = (__bf16)acc[m][n][r];
        }
  }
}

// ---------------------------------------------------------------------------
// proj_out: 128x64 tile (m97 staging) -> grid (16,32)=512 blocks, 2/CU.
// ---------------------------------------------------------------------------
__global__ __launch_bounds__(256) void proj_out(const __bf16* __restrict__ Aattn,
                                                const __bf16* __restrict__ Wo,
                                                float* __restrict__ Out) {
  __shared__ alignas(16) __bf16 As[128 * 64];  // 16 KB
  __shared__ alignas(16) __bf16 Bs[64 * 64];   // 8 KB

  const int tid = threadIdx.x, ln = tid & 63, wv = tid >> 6;
  const int wr = wv >> 1, wc = wv & 1;
  const int fr = ln & 15, fg = ln >> 4;
  const int bm = blockIdx.y * 128, bn = blockIdx.x * 64;

  f32x4 acc[4][2];
#pragma unroll
  for (int m = 0; m < 4; ++m)
#pragma unroll
    for (int n = 0; n < 2; ++n) acc[m][n] = (f32x4){0.f, 0.f, 0.f, 0.f};

  for (int kt = 0; kt < 1024; kt += 64) {
    __syncthreads();
#pragma unroll
    for (int i = 0; i < 4; ++i) {  // A: 16 chunks of 1KB
      const int c = wv * 4 + i;
      const int byte = c * 1024 + ln * 16;
      const int row = byte >> 7;
      const int col = (byte & 127) >> 1;
      const __bf16* ga = Aattn + (size_t)(bm + row) * 1024 + kt + col;
      __builtin_amdgcn_global_load_lds((gas_u32)ga, (las_u32)(As + c * 512), 16, 0, 0);
    }
#pragma unroll
    for (int i = 0; i < 2; ++i) {  // B: 8 chunks of 1KB
      const int c = wv * 2 + i;
      const int byte = c * 1024 + ln * 16;
      const int row = byte >> 7;
      const int col = (byte & 127) >> 1;
      const __bf16* gb = Wo + (size_t)(bn + row) * 1024 + kt + col;
      __builtin_amdgcn_global_load_lds((gas_u32)gb, (las_u32)(Bs + c * 512), 16, 0, 0);
    }
    __syncthreads();

#pragma unroll
    for (int kk = 0; kk < 2; ++kk) {
      const int kc = kk * 32 + fg * 8;
      bf16x8 af[4], bfv[2];
#pragma unroll
      for (int m = 0; m < 4; ++m)
        af[m] = *(const bf16x8*)&As[(wr * 64 + m * 16 + fr) * 64 + kc];
#pragma unroll
      for (int n = 0; n < 2; ++n)
        bfv[n] = *(const bf16x8*)&Bs[(wc * 32 + n * 16 + fr) * 64 + kc];
#pragma unroll
      for (int m = 0; m < 4; ++m)
#pragma unroll
        for (int n = 0; n < 2; ++n) acc[m][n] = MFMA16(af[m], bfv[n], acc[m][n]);
    }
  }

#pragma unroll
  for (int m = 0; m < 4; ++m)
#pragma unroll
    for (int n = 0; n < 2; ++n)
#pragma unroll
      for (int r = 0; r < 4; ++r) {
        const int row = bm + wr * 64 + m * 16 + fg * 4 + r;
        const int col = bn + wc * 32 + n * 16 + fr;
        Out[(size_t)row * 1024 + col] = acc[m][n][r];
      }
}

// ---------------------------------------------------------------------------
// Flash attention, causal (R21). Paired q-tiles, 8 waves; quad-buffered K/V
// with early-issue staging (vmcnt(4) steady); swapped QK^T, packed P-writes,
// m=0 exp2 softmax. XCD-grouped block map.
// ---------------------------------------------------------------------------
__device__ __forceinline__ int SWZ(int row, int col) {
  return row * 64 + (col ^ ((row & 7) << 3));
}

__global__ __launch_bounds__(512, 2) void flash_attn(
    const __bf16* __restrict__ Q, const __bf16* __restrict__ K,
    const __bf16* __restrict__ Vt, __bf16* __restrict__ O) {
  __shared__ alignas(16) __bf16 Ks[4][64 * 64];   // 32 KB (quad buffer)
  __shared__ alignas(16) __bf16 Vs[4][64 * 64];   // 32 KB
  __shared__ alignas(16) __bf16 Ps[8][16 * 64];   // 16 KB

  const int f  = blockIdx.x;            // 0..511
  const int x  = f & 7, w = f >> 3;
  const int bh = x * 4 + (w >> 4);
  const int j  = w & 15;                // lo tile; hi = NT-1-j
  const int hi = NT - 1 - j;
  const int b  = bh >> 4;
  const int h  = bh & 15;

  const int tid  = threadIdx.x;
  const int lane = tid & 63, wave = tid >> 6;
  const int grp = wave >> 2, w4 = wave & 3;   // grp 0 -> hi rows, 1 -> lo rows
  const int fr = lane & 15, fg = lane >> 4;

  const int srow = wave * 8 + (lane >> 3);               // 0..63
  const int gp   = (lane & 7) ^ ((lane >> 3) & 7);       // swizzled src granule

  const int myqt = grp ? j : hi;        // this wave-group's q-tile
  const __bf16* Kh = K + (size_t)b * SEQ * D_MODEL + h * DKH;
  const __bf16* Vh = Vt + (size_t)(bh * DKH) * SEQ;

  auto stage = [&](int buf, int t) {
    const __bf16* ks = Kh + (size_t)(t * KB + srow) * D_MODEL + gp * 8;
    __builtin_amdgcn_global_load_lds((gas_u32)ks, (las_u32)(&Ks[buf][wave * 512]),
                                     16, 0, 0);
    const __bf16* vs = Vh + (size_t)srow * SEQ + t * KB + gp * 8;
    __builtin_amdgcn_global_load_lds((gas_u32)vs, (las_u32)(&Vs[buf][wave * 512]),
                                     16, 0, 0);
  };

  f32x4 acc[4];
#pragma unroll
  for (int n = 0; n < 4; ++n) acc[n] = (f32x4){0.f, 0.f, 0.f, 0.f};
  f32x4 l4 = (f32x4){0.f, 0.f, 0.f, 0.f};

  bf16x8 q0, q1;
  {
    const size_t qrow = (size_t)(b * SEQ + myqt * QB + w4 * 16 + fr) * D_MODEL + h * DKH;
    q0 = *(const bf16x8*)(Q + qrow + fg * 8);
    q1 = *(const bf16x8*)(Q + qrow + 32 + fg * 8);
  }

  const bf16x8 ones = {(__bf16)1.f, (__bf16)1.f, (__bf16)1.f, (__bf16)1.f,
                       (__bf16)1.f, (__bf16)1.f, (__bf16)1.f, (__bf16)1.f};

  auto step = [&](const int t, const int cur, __bf16* __restrict__ ps) {
    f32x4 s[4];
    __builtin_amdgcn_s_setprio(1);
#pragma unroll
    for (int kb = 0; kb < 4; ++kb) {
      f32x4 a = (f32x4){0.f, 0.f, 0.f, 0.f};
      bf16x8 kf0 = *(const bf16x8*)&Ks[cur][SWZ(kb * 16 + fr, fg * 8)];
      bf16x8 kf1 = *(const bf16x8*)&Ks[cur][SWZ(kb * 16 + fr, 32 + fg * 8)];
      a = MFMA16(kf0, q0, a);
      a = MFMA16(kf1, q1, a);
      s[kb] = a;
    }
    __builtin_amdgcn_s_setprio(0);

    if (t == myqt) {
      const int qin = w4 * 16 + fr;
#pragma unroll
      for (int kb = 0; kb < 4; ++kb)
#pragma unroll
        for (int r = 0; r < 4; ++r)
          if (kb * 16 + fg * 4 + r > qin) s[kb][r] = -INFINITY;
    }

#pragma unroll
    for (int kb = 0; kb < 4; ++kb) {
      bf16x4 wv = {(__bf16)__builtin_amdgcn_exp2f(s[kb][0]),
                   (__bf16)__builtin_amdgcn_exp2f(s[kb][1]),
                   (__bf16)__builtin_amdgcn_exp2f(s[kb][2]),
                   (__bf16)__builtin_amdgcn_exp2f(s[kb][3])};
      *(bf16x4*)&ps[SWZ(fr, kb * 16 + fg * 4)] = wv;
    }

    __builtin_amdgcn_s_setprio(1);
#pragma unroll
    for (int k2 = 0; k2 < 2; ++k2) {
      bf16x8 pf = *(const bf16x8*)&ps[SWZ(fr, k2 * 32 + fg * 8)];
#pragma unroll
      for (int n = 0; n < 4; ++n) {
        bf16x8 vf = *(const bf16x8*)&Vs[cur][SWZ(n * 16 + fr, k2 * 32 + fg * 8)];
        acc[n] = MFMA16(pf, vf, acc[n]);
      }
      l4 = MFMA16(pf, ones, l4);
    }
    __builtin_amdgcn_s_setprio(0);
  };

  // prologue: 2 tiles in flight (hi >= 16 always, so tile 1 exists)
  stage(0, 0);
  stage(1, 1);

#pragma unroll 1
  for (int t = 0; t <= hi; ++t) {
    if (t + 2 <= hi) stage((t + 2) & 3, t + 2);

    if (t < hi) asm volatile("s_waitcnt vmcnt(4)" ::: "memory");
    else        asm volatile("s_waitcnt vmcnt(0)" ::: "memory");
    __builtin_amdgcn_s_barrier();

    if (t <= myqt) step(t, t & 3, &Ps[wave][0]);
  }

  // epilogue: O = acc / l  (each wave owns its rows; no merge)
  {
    const size_t obase = (size_t)(b * SEQ + myqt * QB + w4 * 16) * D_MODEL + h * DKH;
#pragma unroll
    for (int n = 0; n < 4; ++n)
#pragma unroll
      for (int r = 0; r < 4; ++r) {
        const int row = fg * 4 + r;
        O[obase + (size_t)row * D_MODEL + n * 16 + fr] =
            (__bf16)(acc[n][r] / l4[r]);
      }
  }
}

// ---------------------------------------------------------------------------
extern "C" void kernel_launch(void* const* d_in, const int* in_sizes, int n_in,
                              void* d_out, int out_size, void* d_ws, size_t ws_size,
                              hipStream_t stream) {
  const float* q_src = (const float*)d_in[0];
  const float* k_src = (const float*)d_in[1];
  const float* v_src = (const float*)d_in[2];
  // d_in[3] = causal tril mask (fixed) -> applied analytically
  const float* Wq = (const float*)d_in[4];
  const float* Wk = (const float*)d_in[5];
  const float* Wv = (const float*)d_in[6];
  const float* Wo = (const float*)d_in[7];

  const size_t NE = (size_t)M_ROWS * D_MODEL;  // 4M elems
  const size_t NW = (size_t)D_MODEL * D_MODEL; // 1M elems
  __bf16* Xq  = (__bf16*)d_ws;
  __bf16* Xk  = Xq + NE;
  __bf16* Xv  = Xk + NE;
  __bf16* Wqb = Xv + NE;
  __bf16* Wkb = Wqb + NW;
  __bf16* Wvb = Wkb + NW;
  __bf16* Wob = Wvb + NW;
  __bf16* Q   = Wob + NW;
  __bf16* K   = Q + NE;
  __bf16* Vt  = K + NE;
  __bf16* A   = Xq;  // Xq consumed by proj_qkv before flash writes A

  CvtArgs ca;
  ca.src[0] = q_src; ca.dst[0] = Xq;  ca.n8[0] = (int)(NE / 8);
  ca.src[1] = k_src; ca.dst[1] = Xk;  ca.n8[1] = (int)(NE / 8);
  ca.src[2] = v_src; ca.dst[2] = Xv;  ca.n8[2] = (int)(NE / 8);
  ca.src[3] = Wq;    ca.dst[3] = Wqb; ca.n8[3] = (int)(NW / 8);  // x0.125*log2e
  ca.src[4] = Wk;    ca.dst[4] = Wkb; ca.n8[4] = (int)(NW / 8);
  ca.src[5] = Wv;    ca.dst[5] = Wvb; ca.n8[5] = (int)(NW / 8);
  ca.src[6] = Wo;    ca.dst[6] = Wob; ca.n8[6] = (int)(NW / 8);

  cvt_bf16<<<dim3((unsigned)(NE / 8 / 256), 1, 7), dim3(256), 0, stream>>>(ca);
  proj_qkv<<<dim3(4, 16, 3), dim3(1024), 0, stream>>>(
      Xq, Xk, Xv, Wqb, Wkb, Wvb, Q, K, Vt);
  flash_attn<<<dim3(NT * BATCH * HEADS / 2), dim3(512), 0, stream>>>(Q, K, Vt, A);
  proj_out<<<dim3(D_MODEL / 64, M_ROWS / 128), dim3(256), 0, stream>>>(
      A, Wob, (float*)d_out);
}

// Round 23
// 112.383 us; speedup vs baseline: 1.0827x; 1.0827x over previous
//
#include <hip/hip_runtime.h>
#include <hip/hip_bf16.h>

// MultiheadAttention: out = (softmax_causal((Xq Wq^T)(Xk Wk^T)^T / 8) (Xv Wv^T)) Wo^T
// B=2 S=2048 D=1024 H=16 dk=64. bf16 MFMA (16x16x32), fp32 accum.
// R23: pure revert to R21 (measured best, 112.4us). R22's 16-wave proj_qkv
//      spilled at VGPR=64 (WRITE_SIZE +8MB scratch) — wave-widening
//      falsified; 8-wave R19 schedule restored.

typedef __attribute__((ext_vector_type(8))) __bf16 bf16x8;
typedef __attribute__((ext_vector_type(4))) __bf16 bf16x4;
typedef __attribute__((ext_vector_type(4))) float f32x4;

#define MFMA16(a, b, c) __builtin_amdgcn_mfma_f32_16x16x32_bf16((a), (b), (c), 0, 0, 0)

constexpr int D_MODEL = 1024;
constexpr int HEADS   = 16;
constexpr int DKH     = 64;
constexpr int BATCH   = 2;
constexpr int SEQ     = 2048;
constexpr int M_ROWS  = BATCH * SEQ;  // 4096
constexpr int QB = 64, KB = 64, NT = SEQ / QB;  // 32 q-tiles

typedef const unsigned int __attribute__((address_space(1)))* gas_u32;
typedef unsigned int __attribute__((address_space(3)))* las_u32;

// ---------------------------------------------------------------------------
// fp32 -> bf16 convert; seg 3 (Wq) pre-scaled by 0.125*log2(e) (exp2 softmax).
// Segs 0-5 granule-swizzled for the 8-phase GEMM staging (rule #21).
// ---------------------------------------------------------------------------
struct CvtArgs {
  const float* src[7];
  __bf16* dst[7];
  int n8[7];
};

__global__ __launch_bounds__(256) void cvt_bf16(CvtArgs a) {
  const int z = blockIdx.z;
  const int i = blockIdx.x * 256 + threadIdx.x;
  if (i >= a.n8[z]) return;
  const float sc = (z == 3) ? 0.18033688011112042f : 1.0f;  // 0.125*log2e
  const float4* s = (const float4*)a.src[z] + (size_t)i * 2;
  float4 x = s[0], y = s[1];
  bf16x8 o = {(__bf16)(x.x * sc), (__bf16)(x.y * sc), (__bf16)(x.z * sc), (__bf16)(x.w * sc),
              (__bf16)(y.x * sc), (__bf16)(y.y * sc), (__bf16)(y.z * sc), (__bf16)(y.w * sc)};
  size_t oi = (size_t)i;
  if (z < 6) {
    const int row = i >> 7;  // 1024 elems = 128 granules per row
    oi = (size_t)((i & ~7) | ((i & 7) ^ (row & 7)));
  }
  *(bf16x8*)(a.dst[z] + oi * 8) = o;
}

// ---------------------------------------------------------------------------
// 8-phase 256x256 GEMM (R19 schedule: 3-half-tile slack, vmcnt(6)/(4))
// ---------------------------------------------------------------------------
__global__ __launch_bounds__(512, 2) void proj_qkv(
    const __bf16* __restrict__ Xq, const __bf16* __restrict__ Xk,
    const __bf16* __restrict__ Xv, const __bf16* __restrict__ Wq,
    const __bf16* __restrict__ Wk, const __bf16* __restrict__ Wv,
    __bf16* __restrict__ Q, __bf16* __restrict__ K, __bf16* __restrict__ Vt) {
  __shared__ alignas(16) __bf16 As[2 * 256 * 64];  // 64 KB
  __shared__ alignas(16) __bf16 Bs[2 * 256 * 64];  // 64 KB

  int f = (blockIdx.z * gridDim.y + blockIdx.y) * gridDim.x + blockIdx.x;
  f = (f & 7) * 24 + (f >> 3);
  const int bx = f & 3, by = (f >> 2) & 15, bz = f >> 6;

  const __bf16* Ag; const __bf16* Bg;
  if (bz == 0)      { Ag = Xq; Bg = Wq; }
  else if (bz == 1) { Ag = Xk; Bg = Wk; }
  else              { Ag = Xv; Bg = Wv; }

  const int bm = by * 256, bn = bx * 256;
  const int tid = threadIdx.x, ln = tid & 63, wv = tid >> 6;
  const int wr = wv >> 2, wc = wv & 3;
  const int fr = ln & 15, fg = ln >> 4;

  auto stageA = [&](int buf, int h, int t) {
    const int kt = t * 64;
#pragma unroll
    for (int l = 0; l < 2; ++l) {
      const int gbase = l * 512 + wv * 64;
      const int d = gbase + ln;
      const __bf16* src = Ag + (size_t)(bm + h * 128 + (d >> 3)) * 1024 + kt + (d & 7) * 8;
      __builtin_amdgcn_global_load_lds((gas_u32)src,
          (las_u32)(As + (size_t)(buf * 2048 + h * 1024 + gbase) * 8), 16, 0, 0);
    }
  };
  auto stageB = [&](int buf, int h, int t) {
    const int kt = t * 64;
#pragma unroll
    for (int l = 0; l < 2; ++l) {
      const int gbase = l * 512 + wv * 64;
      const int d = gbase + ln;
      const __bf16* src = Bg + (size_t)(bn + h * 128 + (d >> 3)) * 1024 + kt + (d & 7) * 8;
      __builtin_amdgcn_global_load_lds((gas_u32)src,
          (las_u32)(Bs + (size_t)(buf * 2048 + h * 1024 + gbase) * 8), 16, 0, 0);
    }
  };

  f32x4 acc[8][4];
#pragma unroll
  for (int m = 0; m < 8; ++m)
#pragma unroll
    for (int n = 0; n < 4; ++n) acc[m][n] = (f32x4){0.f, 0.f, 0.f, 0.f};

  bf16x8 ra[4][2], rb[4][2];

  auto loadA = [&](int buf, int mbase) {
#pragma unroll
    for (int m = 0; m < 4; ++m)
#pragma unroll
      for (int kk = 0; kk < 2; ++kk) {
        const int row = wr * 128 + (mbase + m) * 16 + fr;
        ra[m][kk] = *(const bf16x8*)&As[(buf * 256 + row) * 64 +
                                        (((kk * 4 + fg) ^ (row & 7)) << 3)];
      }
  };
  auto loadB = [&](int buf, int n0) {
#pragma unroll
    for (int n = 0; n < 2; ++n)
#pragma unroll
      for (int kk = 0; kk < 2; ++kk) {
        const int row = wc * 64 + (n0 + n) * 16 + fr;
        rb[n0 + n][kk] = *(const bf16x8*)&Bs[(buf * 256 + row) * 64 +
                                             (((kk * 4 + fg) ^ (row & 7)) << 3)];
      }
  };
  auto quad = [&](int mb, int nb) {
    __builtin_amdgcn_s_setprio(1);
#pragma unroll
    for (int m = 0; m < 4; ++m)
#pragma unroll
      for (int n = 0; n < 2; ++n) {
        acc[mb + m][nb + n] = MFMA16(ra[m][0], rb[nb + n][0], acc[mb + m][nb + n]);
        acc[mb + m][nb + n] = MFMA16(ra[m][1], rb[nb + n][1], acc[mb + m][nb + n]);
      }
    __builtin_amdgcn_s_setprio(0);
  };

  stageB(0, 0, 0); stageB(0, 1, 0); stageA(0, 0, 0); stageA(0, 1, 0);
  stageB(1, 0, 1); stageA(1, 0, 1);
  asm volatile("s_waitcnt vmcnt(4)" ::: "memory");
  __builtin_amdgcn_s_barrier();

#pragma unroll 1
  for (int it = 0; it < 8; ++it) {
    const int T0 = 2 * it, T1 = 2 * it + 1;
    const bool nl = (it < 7);

    loadA(0, 0); loadB(0, 0); loadB(0, 2);
    stageB(1, 1, T1);
    __builtin_amdgcn_s_barrier();
    quad(0, 0);
    __builtin_amdgcn_s_barrier();

    stageA(1, 1, T1);
    if (nl) stageB(0, 0, T0 + 2);
    __builtin_amdgcn_s_barrier();
    quad(0, 2);
    __builtin_amdgcn_s_barrier();

    loadA(0, 4);
    if (nl) stageB(0, 1, T0 + 2);
    __builtin_amdgcn_s_barrier();
    quad(4, 0);
    __builtin_amdgcn_s_barrier();

    if (nl) {
      stageA(0, 0, T0 + 2);
      asm volatile("s_waitcnt vmcnt(6)" ::: "memory");
    } else {
      asm volatile("s_waitcnt vmcnt(0)" ::: "memory");
    }
    __builtin_amdgcn_s_barrier();
    quad(4, 2);
    __builtin_amdgcn_s_barrier();

    loadA(1, 0); loadB(1, 0); loadB(1, 2);
    if (nl) stageA(0, 1, T0 + 2);
    __builtin_amdgcn_s_barrier();
    quad(0, 0);
    __builtin_amdgcn_s_barrier();

    if (nl) stageB(1, 0, T1 + 2);
    __builtin_amdgcn_s_barrier();
    quad(0, 2);
    __builtin_amdgcn_s_barrier();

    loadA(1, 4);
    __builtin_amdgcn_s_barrier();
    quad(4, 0);
    __builtin_amdgcn_s_barrier();

    if (nl) {
      stageA(1, 0, T1 + 2);
      asm volatile("s_waitcnt vmcnt(4)" ::: "memory");
    }
    __builtin_amdgcn_s_barrier();
    quad(4, 2);
    __builtin_amdgcn_s_barrier();
  }

  if (bz == 2) {
    const int b = bm >> 11;
#pragma unroll
    for (int m = 0; m < 8; ++m)
#pragma unroll
      for (int n = 0; n < 4; ++n) {
        const int col = bn + wc * 64 + n * 16 + fr;
        const int s0  = (bm + wr * 128 + m * 16 + fg * 4) & (SEQ - 1);
        bf16x4 o = {(__bf16)acc[m][n][0], (__bf16)acc[m][n][1],
                    (__bf16)acc[m][n][2], (__bf16)acc[m][n][3]};
        *(bf16x4*)(Vt + (((size_t)(b * 1024 + col)) << 11) + s0) = o;
      }
  } else {
    __bf16* C = (bz == 0) ? Q : K;
#pragma unroll
    for (int m = 0; m < 8; ++m)
#pragma unroll
      for (int n = 0; n < 4; ++n)
#pragma unroll
        for (int r = 0; r < 4; ++r) {
          const int row = bm + wr * 128 + m * 16 + fg * 4 + r;
          const int col = bn + wc * 64 + n * 16 + fr;
          C[(size_t)row * 1024 + col] = (__bf16)acc[m][n][r];
        }
  }
}

// ---------------------------------------------------------------------------
// proj_out: 128x64 tile (m97 staging) -> grid (16,32)=512 blocks, 2/CU.
// ---------------------------------------------------------------------------
__global__ __launch_bounds__(256) void proj_out(const __bf16* __restrict__ Aattn,
                                                const __bf16* __restrict__ Wo,
                                                float* __restrict__ Out) {
  __shared__ alignas(16) __bf16 As[128 * 64];  // 16 KB
  __shared__ alignas(16) __bf16 Bs[64 * 64];   // 8 KB

  const int tid = threadIdx.x, ln = tid & 63, wv = tid >> 6;
  const int wr = wv >> 1, wc = wv & 1;
  const int fr = ln & 15, fg = ln >> 4;
  const int bm = blockIdx.y * 128, bn = blockIdx.x * 64;

  f32x4 acc[4][2];
#pragma unroll
  for (int m = 0; m < 4; ++m)
#pragma unroll
    for (int n = 0; n < 2; ++n) acc[m][n] = (f32x4){0.f, 0.f, 0.f, 0.f};

  for (int kt = 0; kt < 1024; kt += 64) {
    __syncthreads();
#pragma unroll
    for (int i = 0; i < 4; ++i) {  // A: 16 chunks of 1KB
      const int c = wv * 4 + i;
      const int byte = c * 1024 + ln * 16;
      const int row = byte >> 7;
      const int col = (byte & 127) >> 1;
      const __bf16* ga = Aattn + (size_t)(bm + row) * 1024 + kt + col;
      __builtin_amdgcn_global_load_lds((gas_u32)ga, (las_u32)(As + c * 512), 16, 0, 0);
    }
#pragma unroll
    for (int i = 0; i < 2; ++i) {  // B: 8 chunks of 1KB
      const int c = wv * 2 + i;
      const int byte = c * 1024 + ln * 16;
      const int row = byte >> 7;
      const int col = (byte & 127) >> 1;
      const __bf16* gb = Wo + (size_t)(bn + row) * 1024 + kt + col;
      __builtin_amdgcn_global_load_lds((gas_u32)gb, (las_u32)(Bs + c * 512), 16, 0, 0);
    }
    __syncthreads();

#pragma unroll
    for (int kk = 0; kk < 2; ++kk) {
      const int kc = kk * 32 + fg * 8;
      bf16x8 af[4], bfv[2];
#pragma unroll
      for (int m = 0; m < 4; ++m)
        af[m] = *(const bf16x8*)&As[(wr * 64 + m * 16 + fr) * 64 + kc];
#pragma unroll
      for (int n = 0; n < 2; ++n)
        bfv[n] = *(const bf16x8*)&Bs[(wc * 32 + n * 16 + fr) * 64 + kc];
#pragma unroll
      for (int m = 0; m < 4; ++m)
#pragma unroll
        for (int n = 0; n < 2; ++n) acc[m][n] = MFMA16(af[m], bfv[n], acc[m][n]);
    }
  }

#pragma unroll
  for (int m = 0; m < 4; ++m)
#pragma unroll
    for (int n = 0; n < 2; ++n)
#pragma unroll
      for (int r = 0; r < 4; ++r) {
        const int row = bm + wr * 64 + m * 16 + fg * 4 + r;
        const int col = bn + wc * 32 + n * 16 + fr;
        Out[(size_t)row * 1024 + col] = acc[m][n][r];
      }
}

// ---------------------------------------------------------------------------
// Flash attention, causal. Paired q-tiles (hi, lo), 8 waves; shared K/V
// stream; QUAD-buffered K/V via global_load_lds with EARLY-ISSUE staging
// (stage(t+2) before the wait; vmcnt(4) steady); swapped QK^T, packed
// P-writes, m=0 exp2 softmax. XCD-grouped block map.
// ---------------------------------------------------------------------------
__device__ __forceinline__ int SWZ(int row, int col) {
  return row * 64 + (col ^ ((row & 7) << 3));
}

__global__ __launch_bounds__(512, 2) void flash_attn(
    const __bf16* __restrict__ Q, const __bf16* __restrict__ K,
    const __bf16* __restrict__ Vt, __bf16* __restrict__ O) {
  __shared__ alignas(16) __bf16 Ks[4][64 * 64];   // 32 KB (quad buffer)
  __shared__ alignas(16) __bf16 Vs[4][64 * 64];   // 32 KB
  __shared__ alignas(16) __bf16 Ps[8][16 * 64];   // 16 KB

  const int f  = blockIdx.x;            // 0..511
  const int x  = f & 7, w = f >> 3;
  const int bh = x * 4 + (w >> 4);
  const int j  = w & 15;                // lo tile; hi = NT-1-j
  const int hi = NT - 1 - j;
  const int b  = bh >> 4;
  const int h  = bh & 15;

  const int tid  = threadIdx.x;
  const int lane = tid & 63, wave = tid >> 6;
  const int grp = wave >> 2, w4 = wave & 3;   // grp 0 -> hi rows, 1 -> lo rows
  const int fr = lane & 15, fg = lane >> 4;

  const int srow = wave * 8 + (lane >> 3);               // 0..63
  const int gp   = (lane & 7) ^ ((lane >> 3) & 7);       // swizzled src granule

  const int myqt = grp ? j : hi;        // this wave-group's q-tile
  const __bf16* Kh = K + (size_t)b * SEQ * D_MODEL + h * DKH;
  const __bf16* Vh = Vt + (size_t)(bh * DKH) * SEQ;

  auto stage = [&](int buf, int t) {
    const __bf16* ks = Kh + (size_t)(t * KB + srow) * D_MODEL + gp * 8;
    __builtin_amdgcn_global_load_lds((gas_u32)ks, (las_u32)(&Ks[buf][wave * 512]),
                                     16, 0, 0);
    const __bf16* vs = Vh + (size_t)srow * SEQ + t * KB + gp * 8;
    __builtin_amdgcn_global_load_lds((gas_u32)vs, (las_u32)(&Vs[buf][wave * 512]),
                                     16, 0, 0);
  };

  f32x4 acc[4];
#pragma unroll
  for (int n = 0; n < 4; ++n) acc[n] = (f32x4){0.f, 0.f, 0.f, 0.f};
  f32x4 l4 = (f32x4){0.f, 0.f, 0.f, 0.f};

  bf16x8 q0, q1;
  {
    const size_t qrow = (size_t)(b * SEQ + myqt * QB + w4 * 16 + fr) * D_MODEL + h * DKH;
    q0 = *(const bf16x8*)(Q + qrow + fg * 8);
    q1 = *(const bf16x8*)(Q + qrow + 32 + fg * 8);
  }

  const bf16x8 ones = {(__bf16)1.f, (__bf16)1.f, (__bf16)1.f, (__bf16)1.f,
                       (__bf16)1.f, (__bf16)1.f, (__bf16)1.f, (__bf16)1.f};

  auto step = [&](const int t, const int cur, __bf16* __restrict__ ps) {
    f32x4 s[4];
    __builtin_amdgcn_s_setprio(1);
#pragma unroll
    for (int kb = 0; kb < 4; ++kb) {
      f32x4 a = (f32x4){0.f, 0.f, 0.f, 0.f};
      bf16x8 kf0 = *(const bf16x8*)&Ks[cur][SWZ(kb * 16 + fr, fg * 8)];
      bf16x8 kf1 = *(const bf16x8*)&Ks[cur][SWZ(kb * 16 + fr, 32 + fg * 8)];
      a = MFMA16(kf0, q0, a);
      a = MFMA16(kf1, q1, a);
      s[kb] = a;
    }
    __builtin_amdgcn_s_setprio(0);

    if (t == myqt) {  // causal mask, lane-local
      const int qin = w4 * 16 + fr;
#pragma unroll
      for (int kb = 0; kb < 4; ++kb)
#pragma unroll
        for (int r = 0; r < 4; ++r)
          if (kb * 16 + fg * 4 + r > qin) s[kb][r] = -INFINITY;
    }

    // P = exp2(s) via raw v_exp_f32; packed b64 write per kb
#pragma unroll
    for (int kb = 0; kb < 4; ++kb) {
      bf16x4 wv = {(__bf16)__builtin_amdgcn_exp2f(s[kb][0]),
                   (__bf16)__builtin_amdgcn_exp2f(s[kb][1]),
                   (__bf16)__builtin_amdgcn_exp2f(s[kb][2]),
                   (__bf16)__builtin_amdgcn_exp2f(s[kb][3])};
      *(bf16x4*)&ps[SWZ(fr, kb * 16 + fg * 4)] = wv;
    }

    __builtin_amdgcn_s_setprio(1);
#pragma unroll
    for (int k2 = 0; k2 < 2; ++k2) {
      bf16x8 pf = *(const bf16x8*)&ps[SWZ(fr, k2 * 32 + fg * 8)];
#pragma unroll
      for (int n = 0; n < 4; ++n) {
        bf16x8 vf = *(const bf16x8*)&Vs[cur][SWZ(n * 16 + fr, k2 * 32 + fg * 8)];
        acc[n] = MFMA16(pf, vf, acc[n]);
      }
      l4 = MFMA16(pf, ones, l4);
    }
    __builtin_amdgcn_s_setprio(0);
  };

  // prologue: 2 tiles in flight (hi >= 16 always, so tile 1 exists)
  stage(0, 0);
  stage(1, 1);

#pragma unroll 1
  for (int t = 0; t <= hi; ++t) {
    // EARLY ISSUE: stage(t+2) into buf (t+2)&3 before the wait; newest 4
    // outstanding = tiles t+1,t+2 -> vmcnt(4) proves tile t landed.
    if (t + 2 <= hi) stage((t + 2) & 3, t + 2);

    if (t < hi) asm volatile("s_waitcnt vmcnt(4)" ::: "memory");
    else        asm volatile("s_waitcnt vmcnt(0)" ::: "memory");
    __builtin_amdgcn_s_barrier();

    if (t <= myqt) step(t, t & 3, &Ps[wave][0]);
  }

  // epilogue: O = acc / l  (each wave owns its rows; no merge)
  {
    const size_t obase = (size_t)(b * SEQ + myqt * QB + w4 * 16) * D_MODEL + h * DKH;
#pragma unroll
    for (int n = 0; n < 4; ++n)
#pragma unroll
      for (int r = 0; r < 4; ++r) {
        const int row = fg * 4 + r;
        O[obase + (size_t)row * D_MODEL + n * 16 + fr] =
            (__bf16)(acc[n][r] / l4[r]);
      }
  }
}

// ---------------------------------------------------------------------------
extern "C" void kernel_launch(void* const* d_in, const int* in_sizes, int n_in,
                              void* d_out, int out_size, void* d_ws, size_t ws_size,
                              hipStream_t stream) {
  const float* q_src = (const float*)d_in[0];
  const float* k_src = (const float*)d_in[1];
  const float* v_src = (const float*)d_in[2];
  // d_in[3] = causal tril mask (fixed) -> applied analytically
  const float* Wq = (const float*)d_in[4];
  const float* Wk = (const float*)d_in[5];
  const float* Wv = (const float*)d_in[6];
  const float* Wo = (const float*)d_in[7];

  const size_t NE = (size_t)M_ROWS * D_MODEL;  // 4M elems
  const size_t NW = (size_t)D_MODEL * D_MODEL; // 1M elems
  __bf16* Xq  = (__bf16*)d_ws;
  __bf16* Xk  = Xq + NE;
  __bf16* Xv  = Xk + NE;
  __bf16* Wqb = Xv + NE;
  __bf16* Wkb = Wqb + NW;
  __bf16* Wvb = Wkb + NW;
  __bf16* Wob = Wvb + NW;
  __bf16* Q   = Wob + NW;
  __bf16* K   = Q + NE;
  __bf16* Vt  = K + NE;
  __bf16* A   = Xq;  // Xq consumed by proj_qkv before flash writes A

  CvtArgs ca;
  ca.src[0] = q_src; ca.dst[0] = Xq;  ca.n8[0] = (int)(NE / 8);
  ca.src[1] = k_src; ca.dst[1] = Xk;  ca.n8[1] = (int)(NE / 8);
  ca.src[2] = v_src; ca.dst[2] = Xv;  ca.n8[2] = (int)(NE / 8);
  ca.src[3] = Wq;    ca.dst[3] = Wqb; ca.n8[3] = (int)(NW / 8);  // x0.125*log2e
  ca.src[4] = Wk;    ca.dst[4] = Wkb; ca.n8[4] = (int)(NW / 8);
  ca.src[5] = Wv;    ca.dst[5] = Wvb; ca.n8[5] = (int)(NW / 8);
  ca.src[6] = Wo;    ca.dst[6] = Wob; ca.n8[6] = (int)(NW / 8);

  cvt_bf16<<<dim3((unsigned)(NE / 8 / 256), 1, 7), dim3(256), 0, stream>>>(ca);
  proj_qkv<<<dim3(4, 16, 3), dim3(512), 0, stream>>>(
      Xq, Xk, Xv, Wqb, Wkb, Wvb, Q, K, Vt);
  flash_attn<<<dim3(NT * BATCH * HEADS / 2), dim3(512), 0, stream>>>(Q, K, Vt, A);
  proj_out<<<dim3(D_MODEL / 64, M_ROWS / 128), dim3(256), 0, stream>>>(
      A, Wob, (float*)d_out);
}

// Round 24
// 108.465 us; speedup vs baseline: 1.1218x; 1.0361x over previous
//
#include <hip/hip_runtime.h>
#include <hip/hip_bf16.h>

// MultiheadAttention: out = (softmax_causal((Xq Wq^T)(Xk Wk^T)^T / 8) (Xv Wv^T)) Wo^T
// B=2 S=2048 D=1024 H=16 dk=64. bf16 MFMA (16x16x32), fp32 accum.
// R24: flash = KV-split (R18 structure) + XCD-pinned bh map (R20) so the
//      split-induced K/V re-reads are L2 hits (R18's 3.5us/iter was HBM
//      latency, uncovered). One q-tile/block, grid 1024 longest-first;
//      2 groups x 4 waves over half KV ranges; per-group dbuf K/V via
//      global_load_lds; m=0 merge = pure add. LDS 80KB -> 2 blocks/CU.
//      Makespan: longest block 16 iters (was 32). Other kernels = R23.

typedef __attribute__((ext_vector_type(8))) __bf16 bf16x8;
typedef __attribute__((ext_vector_type(4))) __bf16 bf16x4;
typedef __attribute__((ext_vector_type(4))) float f32x4;

#define MFMA16(a, b, c) __builtin_amdgcn_mfma_f32_16x16x32_bf16((a), (b), (c), 0, 0, 0)

constexpr int D_MODEL = 1024;
constexpr int HEADS   = 16;
constexpr int DKH     = 64;
constexpr int BATCH   = 2;
constexpr int SEQ     = 2048;
constexpr int M_ROWS  = BATCH * SEQ;  // 4096
constexpr int QB = 64, KB = 64, NT = SEQ / QB;  // 32 q-tiles

typedef const unsigned int __attribute__((address_space(1)))* gas_u32;
typedef unsigned int __attribute__((address_space(3)))* las_u32;

// ---------------------------------------------------------------------------
// fp32 -> bf16 convert; seg 3 (Wq) pre-scaled by 0.125*log2(e) (exp2 softmax).
// Segs 0-5 granule-swizzled for the 8-phase GEMM staging (rule #21).
// ---------------------------------------------------------------------------
struct CvtArgs {
  const float* src[7];
  __bf16* dst[7];
  int n8[7];
};

__global__ __launch_bounds__(256) void cvt_bf16(CvtArgs a) {
  const int z = blockIdx.z;
  const int i = blockIdx.x * 256 + threadIdx.x;
  if (i >= a.n8[z]) return;
  const float sc = (z == 3) ? 0.18033688011112042f : 1.0f;  // 0.125*log2e
  const float4* s = (const float4*)a.src[z] + (size_t)i * 2;
  float4 x = s[0], y = s[1];
  bf16x8 o = {(__bf16)(x.x * sc), (__bf16)(x.y * sc), (__bf16)(x.z * sc), (__bf16)(x.w * sc),
              (__bf16)(y.x * sc), (__bf16)(y.y * sc), (__bf16)(y.z * sc), (__bf16)(y.w * sc)};
  size_t oi = (size_t)i;
  if (z < 6) {
    const int row = i >> 7;  // 1024 elems = 128 granules per row
    oi = (size_t)((i & ~7) | ((i & 7) ^ (row & 7)));
  }
  *(bf16x8*)(a.dst[z] + oi * 8) = o;
}

// ---------------------------------------------------------------------------
// 8-phase 256x256 GEMM (R19 schedule: 3-half-tile slack, vmcnt(6)/(4))
// ---------------------------------------------------------------------------
__global__ __launch_bounds__(512, 2) void proj_qkv(
    const __bf16* __restrict__ Xq, const __bf16* __restrict__ Xk,
    const __bf16* __restrict__ Xv, const __bf16* __restrict__ Wq,
    const __bf16* __restrict__ Wk, const __bf16* __restrict__ Wv,
    __bf16* __restrict__ Q, __bf16* __restrict__ K, __bf16* __restrict__ Vt) {
  __shared__ alignas(16) __bf16 As[2 * 256 * 64];  // 64 KB
  __shared__ alignas(16) __bf16 Bs[2 * 256 * 64];  // 64 KB

  int f = (blockIdx.z * gridDim.y + blockIdx.y) * gridDim.x + blockIdx.x;
  f = (f & 7) * 24 + (f >> 3);
  const int bx = f & 3, by = (f >> 2) & 15, bz = f >> 6;

  const __bf16* Ag; const __bf16* Bg;
  if (bz == 0)      { Ag = Xq; Bg = Wq; }
  else if (bz == 1) { Ag = Xk; Bg = Wk; }
  else              { Ag = Xv; Bg = Wv; }

  const int bm = by * 256, bn = bx * 256;
  const int tid = threadIdx.x, ln = tid & 63, wv = tid >> 6;
  const int wr = wv >> 2, wc = wv & 3;
  const int fr = ln & 15, fg = ln >> 4;

  auto stageA = [&](int buf, int h, int t) {
    const int kt = t * 64;
#pragma unroll
    for (int l = 0; l < 2; ++l) {
      const int gbase = l * 512 + wv * 64;
      const int d = gbase + ln;
      const __bf16* src = Ag + (size_t)(bm + h * 128 + (d >> 3)) * 1024 + kt + (d & 7) * 8;
      __builtin_amdgcn_global_load_lds((gas_u32)src,
          (las_u32)(As + (size_t)(buf * 2048 + h * 1024 + gbase) * 8), 16, 0, 0);
    }
  };
  auto stageB = [&](int buf, int h, int t) {
    const int kt = t * 64;
#pragma unroll
    for (int l = 0; l < 2; ++l) {
      const int gbase = l * 512 + wv * 64;
      const int d = gbase + ln;
      const __bf16* src = Bg + (size_t)(bn + h * 128 + (d >> 3)) * 1024 + kt + (d & 7) * 8;
      __builtin_amdgcn_global_load_lds((gas_u32)src,
          (las_u32)(Bs + (size_t)(buf * 2048 + h * 1024 + gbase) * 8), 16, 0, 0);
    }
  };

  f32x4 acc[8][4];
#pragma unroll
  for (int m = 0; m < 8; ++m)
#pragma unroll
    for (int n = 0; n < 4; ++n) acc[m][n] = (f32x4){0.f, 0.f, 0.f, 0.f};

  bf16x8 ra[4][2], rb[4][2];

  auto loadA = [&](int buf, int mbase) {
#pragma unroll
    for (int m = 0; m < 4; ++m)
#pragma unroll
      for (int kk = 0; kk < 2; ++kk) {
        const int row = wr * 128 + (mbase + m) * 16 + fr;
        ra[m][kk] = *(const bf16x8*)&As[(buf * 256 + row) * 64 +
                                        (((kk * 4 + fg) ^ (row & 7)) << 3)];
      }
  };
  auto loadB = [&](int buf, int n0) {
#pragma unroll
    for (int n = 0; n < 2; ++n)
#pragma unroll
      for (int kk = 0; kk < 2; ++kk) {
        const int row = wc * 64 + (n0 + n) * 16 + fr;
        rb[n0 + n][kk] = *(const bf16x8*)&Bs[(buf * 256 + row) * 64 +
                                             (((kk * 4 + fg) ^ (row & 7)) << 3)];
      }
  };
  auto quad = [&](int mb, int nb) {
    __builtin_amdgcn_s_setprio(1);
#pragma unroll
    for (int m = 0; m < 4; ++m)
#pragma unroll
      for (int n = 0; n < 2; ++n) {
        acc[mb + m][nb + n] = MFMA16(ra[m][0], rb[nb + n][0], acc[mb + m][nb + n]);
        acc[mb + m][nb + n] = MFMA16(ra[m][1], rb[nb + n][1], acc[mb + m][nb + n]);
      }
    __builtin_amdgcn_s_setprio(0);
  };

  stageB(0, 0, 0); stageB(0, 1, 0); stageA(0, 0, 0); stageA(0, 1, 0);
  stageB(1, 0, 1); stageA(1, 0, 1);
  asm volatile("s_waitcnt vmcnt(4)" ::: "memory");
  __builtin_amdgcn_s_barrier();

#pragma unroll 1
  for (int it = 0; it < 8; ++it) {
    const int T0 = 2 * it, T1 = 2 * it + 1;
    const bool nl = (it < 7);

    loadA(0, 0); loadB(0, 0); loadB(0, 2);
    stageB(1, 1, T1);
    __builtin_amdgcn_s_barrier();
    quad(0, 0);
    __builtin_amdgcn_s_barrier();

    stageA(1, 1, T1);
    if (nl) stageB(0, 0, T0 + 2);
    __builtin_amdgcn_s_barrier();
    quad(0, 2);
    __builtin_amdgcn_s_barrier();

    loadA(0, 4);
    if (nl) stageB(0, 1, T0 + 2);
    __builtin_amdgcn_s_barrier();
    quad(4, 0);
    __builtin_amdgcn_s_barrier();

    if (nl) {
      stageA(0, 0, T0 + 2);
      asm volatile("s_waitcnt vmcnt(6)" ::: "memory");
    } else {
      asm volatile("s_waitcnt vmcnt(0)" ::: "memory");
    }
    __builtin_amdgcn_s_barrier();
    quad(4, 2);
    __builtin_amdgcn_s_barrier();

    loadA(1, 0); loadB(1, 0); loadB(1, 2);
    if (nl) stageA(0, 1, T0 + 2);
    __builtin_amdgcn_s_barrier();
    quad(0, 0);
    __builtin_amdgcn_s_barrier();

    if (nl) stageB(1, 0, T1 + 2);
    __builtin_amdgcn_s_barrier();
    quad(0, 2);
    __builtin_amdgcn_s_barrier();

    loadA(1, 4);
    __builtin_amdgcn_s_barrier();
    quad(4, 0);
    __builtin_amdgcn_s_barrier();

    if (nl) {
      stageA(1, 0, T1 + 2);
      asm volatile("s_waitcnt vmcnt(4)" ::: "memory");
    }
    __builtin_amdgcn_s_barrier();
    quad(4, 2);
    __builtin_amdgcn_s_barrier();
  }

  if (bz == 2) {
    const int b = bm >> 11;
#pragma unroll
    for (int m = 0; m < 8; ++m)
#pragma unroll
      for (int n = 0; n < 4; ++n) {
        const int col = bn + wc * 64 + n * 16 + fr;
        const int s0  = (bm + wr * 128 + m * 16 + fg * 4) & (SEQ - 1);
        bf16x4 o = {(__bf16)acc[m][n][0], (__bf16)acc[m][n][1],
                    (__bf16)acc[m][n][2], (__bf16)acc[m][n][3]};
        *(bf16x4*)(Vt + (((size_t)(b * 1024 + col)) << 11) + s0) = o;
      }
  } else {
    __bf16* C = (bz == 0) ? Q : K;
#pragma unroll
    for (int m = 0; m < 8; ++m)
#pragma unroll
      for (int n = 0; n < 4; ++n)
#pragma unroll
        for (int r = 0; r < 4; ++r) {
          const int row = bm + wr * 128 + m * 16 + fg * 4 + r;
          const int col = bn + wc * 64 + n * 16 + fr;
          C[(size_t)row * 1024 + col] = (__bf16)acc[m][n][r];
        }
  }
}

// ---------------------------------------------------------------------------
// proj_out: 128x64 tile (m97 staging) -> grid (16,32)=512 blocks, 2/CU.
// ---------------------------------------------------------------------------
__global__ __launch_bounds__(256) void proj_out(const __bf16* __restrict__ Aattn,
                                                const __bf16* __restrict__ Wo,
                                                float* __restrict__ Out) {
  __shared__ alignas(16) __bf16 As[128 * 64];  // 16 KB
  __shared__ alignas(16) __bf16 Bs[64 * 64];   // 8 KB

  const int tid = threadIdx.x, ln = tid & 63, wv = tid >> 6;
  const int wr = wv >> 1, wc = wv & 1;
  const int fr = ln & 15, fg = ln >> 4;
  const int bm = blockIdx.y * 128, bn = blockIdx.x * 64;

  f32x4 acc[4][2];
#pragma unroll
  for (int m = 0; m < 4; ++m)
#pragma unroll
    for (int n = 0; n < 2; ++n) acc[m][n] = (f32x4){0.f, 0.f, 0.f, 0.f};

  for (int kt = 0; kt < 1024; kt += 64) {
    __syncthreads();
#pragma unroll
    for (int i = 0; i < 4; ++i) {  // A: 16 chunks of 1KB
      const int c = wv * 4 + i;
      const int byte = c * 1024 + ln * 16;
      const int row = byte >> 7;
      const int col = (byte & 127) >> 1;
      const __bf16* ga = Aattn + (size_t)(bm + row) * 1024 + kt + col;
      __builtin_amdgcn_global_load_lds((gas_u32)ga, (las_u32)(As + c * 512), 16, 0, 0);
    }
#pragma unroll
    for (int i = 0; i < 2; ++i) {  // B: 8 chunks of 1KB
      const int c = wv * 2 + i;
      const int byte = c * 1024 + ln * 16;
      const int row = byte >> 7;
      const int col = (byte & 127) >> 1;
      const __bf16* gb = Wo + (size_t)(bn + row) * 1024 + kt + col;
      __builtin_amdgcn_global_load_lds((gas_u32)gb, (las_u32)(Bs + c * 512), 16, 0, 0);
    }
    __syncthreads();

#pragma unroll
    for (int kk = 0; kk < 2; ++kk) {
      const int kc = kk * 32 + fg * 8;
      bf16x8 af[4], bfv[2];
#pragma unroll
      for (int m = 0; m < 4; ++m)
        af[m] = *(const bf16x8*)&As[(wr * 64 + m * 16 + fr) * 64 + kc];
#pragma unroll
      for (int n = 0; n < 2; ++n)
        bfv[n] = *(const bf16x8*)&Bs[(wc * 32 + n * 16 + fr) * 64 + kc];
#pragma unroll
      for (int m = 0; m < 4; ++m)
#pragma unroll
        for (int n = 0; n < 2; ++n) acc[m][n] = MFMA16(af[m], bfv[n], acc[m][n]);
    }
  }

#pragma unroll
  for (int m = 0; m < 4; ++m)
#pragma unroll
    for (int n = 0; n < 2; ++n)
#pragma unroll
      for (int r = 0; r < 4; ++r) {
        const int row = bm + wr * 64 + m * 16 + fg * 4 + r;
        const int col = bn + wc * 32 + n * 16 + fr;
        Out[(size_t)row * 1024 + col] = acc[m][n][r];
      }
}

// ---------------------------------------------------------------------------
// Flash attention, causal, KV-split + XCD pinning. Block = ONE q-tile; grid
// 1024 (longest qt first across the XCD's 4 bh). 8 waves = 2 groups of 4;
// grp0 KV tiles [0,h0), grp1 [h0,len), len=qt+1, h0=ceil(len/2). Per-group
// dbuf K/V via global_load_lds (pre-swizzled src); issue-top/drain-bottom
// loop (R11/R18 pattern, race-free). Swapped QK^T, packed P-writes, m=0
// exp2 softmax -> merge = pure add. LDS 80KB -> 2 blocks/CU.
// ---------------------------------------------------------------------------
__device__ __forceinline__ int SWZ(int row, int col) {
  return row * 64 + (col ^ ((row & 7) << 3));
}

__global__ __launch_bounds__(512, 2) void flash_attn(
    const __bf16* __restrict__ Q, const __bf16* __restrict__ K,
    const __bf16* __restrict__ Vt, __bf16* __restrict__ O) {
  __shared__ alignas(16) __bf16 Ks[2][2][64 * 64];  // [grp][buf] 32 KB
  __shared__ alignas(16) __bf16 Vs[2][2][64 * 64];  // 32 KB
  __shared__ alignas(16) __bf16 Ps[8][16 * 64];     // 16 KB (reused: merge acc)

  // XCD map: x = f&7 owns bh {4x..4x+3}; within XCD, longest qt first for
  // ALL 4 bh (w>>2 = qt rank), bh = w&3.
  const int f  = blockIdx.x;            // 0..1023
  const int x  = f & 7, w = f >> 3;     // w 0..127
  const int qt = 31 - (w >> 2);         // longest first
  const int bh = x * 4 + (w & 3);
  const int b  = bh >> 4;
  const int h  = bh & 15;

  const int tid  = threadIdx.x;
  const int lane = tid & 63, wave = tid >> 6;
  const int grp = wave >> 2, wg = wave & 3;  // group / wave-in-group
  const int fr = lane & 15, fg = lane >> 4;

  const int len = qt + 1;
  const int h0  = (len + 1) >> 1;       // grp0 [0,h0), grp1 [h0,len)
  const int t0  = grp ? h0 : 0;
  const int tlast = grp ? len : h0;     // exclusive end of this grp's range

  const __bf16* Kh = K + (size_t)b * SEQ * D_MODEL + h * DKH;
  const __bf16* Vh = Vt + (size_t)(bh * DKH) * SEQ;

  // group stages its 64x64 K and V tiles: 4 waves x 2 passes, 1 granule/lane.
  // granule g = p*256 + wg*64 + lane -> row = g>>3; source granule
  // pre-swizzled (g&7)^(row&7) so linear LDS == SWZ layout. 4 gloads/wave.
  auto stage = [&](int buf, int t) {
#pragma unroll
    for (int p = 0; p < 2; ++p) {
      const int row = p * 32 + wg * 8 + (lane >> 3);
      const int sg  = (lane & 7) ^ (row & 7);
      const __bf16* ks = Kh + (size_t)(t * KB + row) * D_MODEL + sg * 8;
      __builtin_amdgcn_global_load_lds((gas_u32)ks,
          (las_u32)(&Ks[grp][buf][(size_t)(p * 256 + wg * 64) * 8]), 16, 0, 0);
      const __bf16* vs = Vh + (size_t)row * SEQ + t * KB + sg * 8;
      __builtin_amdgcn_global_load_lds((gas_u32)vs,
          (las_u32)(&Vs[grp][buf][(size_t)(p * 256 + wg * 64) * 8]), 16, 0, 0);
    }
  };

  f32x4 acc[4];
#pragma unroll
  for (int n = 0; n < 4; ++n) acc[n] = (f32x4){0.f, 0.f, 0.f, 0.f};
  f32x4 l4 = (f32x4){0.f, 0.f, 0.f, 0.f};

  bf16x8 q0, q1;
  {
    const size_t qrow = (size_t)(b * SEQ + qt * QB + wg * 16 + fr) * D_MODEL + h * DKH;
    q0 = *(const bf16x8*)(Q + qrow + fg * 8);
    q1 = *(const bf16x8*)(Q + qrow + 32 + fg * 8);
  }

  const bf16x8 ones = {(__bf16)1.f, (__bf16)1.f, (__bf16)1.f, (__bf16)1.f,
                       (__bf16)1.f, (__bf16)1.f, (__bf16)1.f, (__bf16)1.f};

  auto step = [&](const int t, const int cur, __bf16* __restrict__ ps) {
    // SWAPPED QK^T: lane holds S^T: q = fr, k = kb*16 + fg*4 + r
    f32x4 s[4];
    __builtin_amdgcn_s_setprio(1);
#pragma unroll
    for (int kb = 0; kb < 4; ++kb) {
      f32x4 a = (f32x4){0.f, 0.f, 0.f, 0.f};
      bf16x8 kf0 = *(const bf16x8*)&Ks[grp][cur][SWZ(kb * 16 + fr, fg * 8)];
      bf16x8 kf1 = *(const bf16x8*)&Ks[grp][cur][SWZ(kb * 16 + fr, 32 + fg * 8)];
      a = MFMA16(kf0, q0, a);
      a = MFMA16(kf1, q1, a);
      s[kb] = a;
    }
    __builtin_amdgcn_s_setprio(0);

    if (t == qt) {  // causal mask, lane-local (diagonal KV tile)
      const int qin = wg * 16 + fr;
#pragma unroll
      for (int kb = 0; kb < 4; ++kb)
#pragma unroll
        for (int r = 0; r < 4; ++r)
          if (kb * 16 + fg * 4 + r > qin) s[kb][r] = -INFINITY;
    }

    // P = exp2(s) via raw v_exp_f32; packed b64 write per kb
#pragma unroll
    for (int kb = 0; kb < 4; ++kb) {
      bf16x4 wv = {(__bf16)__builtin_amdgcn_exp2f(s[kb][0]),
                   (__bf16)__builtin_amdgcn_exp2f(s[kb][1]),
                   (__bf16)__builtin_amdgcn_exp2f(s[kb][2]),
                   (__bf16)__builtin_amdgcn_exp2f(s[kb][3])};
      *(bf16x4*)&ps[SWZ(fr, kb * 16 + fg * 4)] = wv;
    }

    __builtin_amdgcn_s_setprio(1);
#pragma unroll
    for (int k2 = 0; k2 < 2; ++k2) {
      bf16x8 pf = *(const bf16x8*)&ps[SWZ(fr, k2 * 32 + fg * 8)];
#pragma unroll
      for (int n = 0; n < 4; ++n) {
        bf16x8 vf = *(const bf16x8*)&Vs[grp][cur][SWZ(n * 16 + fr, k2 * 32 + fg * 8)];
        acc[n] = MFMA16(pf, vf, acc[n]);
      }
      l4 = MFMA16(pf, ones, l4);
    }
    __builtin_amdgcn_s_setprio(0);
  };

  // prologue: stage this grp's first tile (t0 <= 16: valid memory even when
  // grp1's range is empty at len=1)
  stage(0, t0);
  asm volatile("s_waitcnt vmcnt(0)" ::: "memory");
  __syncthreads();

#pragma unroll 1
  for (int i = 0; i < h0; ++i) {
    const int t = t0 + i;
    const int cur = i & 1;

    if (t + 1 < tlast) stage(cur ^ 1, t + 1);  // latency hides under step
    if (t < tlast) step(t, cur, &Ps[wave][0]);

    asm volatile("s_waitcnt vmcnt(0)" ::: "memory");
    __syncthreads();
  }

  // ---- merge (m=0): O = (acc0 + acc1) / (l0 + l1) ----
  float* accb = (float*)&Ps[0][0];        // 4 waves x 16 x 64 f32 = 16 KB
  float* lb   = (float*)&Ks[0][0][0];     // 4 KB scratch (grp0 buf0, done)
  if (grp == 1) {
#pragma unroll
    for (int n = 0; n < 4; ++n)
#pragma unroll
      for (int r = 0; r < 4; ++r)
        accb[(wg * 16 + n * 4 + r) * 64 + lane] = acc[n][r];
#pragma unroll
    for (int r = 0; r < 4; ++r) lb[(wg * 4 + r) * 64 + lane] = l4[r];
  }
  __syncthreads();
  if (grp == 0) {
#pragma unroll
    for (int n = 0; n < 4; ++n)
#pragma unroll
      for (int r = 0; r < 4; ++r) acc[n][r] += accb[(wg * 16 + n * 4 + r) * 64 + lane];
#pragma unroll
    for (int r = 0; r < 4; ++r) l4[r] += lb[(wg * 4 + r) * 64 + lane];

    const size_t obase = (size_t)(b * SEQ + qt * QB + wg * 16) * D_MODEL + h * DKH;
#pragma unroll
    for (int n = 0; n < 4; ++n)
#pragma unroll
      for (int r = 0; r < 4; ++r) {
        const int row = fg * 4 + r;
        O[obase + (size_t)row * D_MODEL + n * 16 + fr] =
            (__bf16)(acc[n][r] / l4[r]);
      }
  }
}

// ---------------------------------------------------------------------------
extern "C" void kernel_launch(void* const* d_in, const int* in_sizes, int n_in,
                              void* d_out, int out_size, void* d_ws, size_t ws_size,
                              hipStream_t stream) {
  const float* q_src = (const float*)d_in[0];
  const float* k_src = (const float*)d_in[1];
  const float* v_src = (const float*)d_in[2];
  // d_in[3] = causal tril mask (fixed) -> applied analytically
  const float* Wq = (const float*)d_in[4];
  const float* Wk = (const float*)d_in[5];
  const float* Wv = (const float*)d_in[6];
  const float* Wo = (const float*)d_in[7];

  const size_t NE = (size_t)M_ROWS * D_MODEL;  // 4M elems
  const size_t NW = (size_t)D_MODEL * D_MODEL; // 1M elems
  __bf16* Xq  = (__bf16*)d_ws;
  __bf16* Xk  = Xq + NE;
  __bf16* Xv  = Xk + NE;
  __bf16* Wqb = Xv + NE;
  __bf16* Wkb = Wqb + NW;
  __bf16* Wvb = Wkb + NW;
  __bf16* Wob = Wvb + NW;
  __bf16* Q   = Wob + NW;
  __bf16* K   = Q + NE;
  __bf16* Vt  = K + NE;
  __bf16* A   = Xq;  // Xq consumed by proj_qkv before flash writes A

  CvtArgs ca;
  ca.src[0] = q_src; ca.dst[0] = Xq;  ca.n8[0] = (int)(NE / 8);
  ca.src[1] = k_src; ca.dst[1] = Xk;  ca.n8[1] = (int)(NE / 8);
  ca.src[2] = v_src; ca.dst[2] = Xv;  ca.n8[2] = (int)(NE / 8);
  ca.src[3] = Wq;    ca.dst[3] = Wqb; ca.n8[3] = (int)(NW / 8);  // x0.125*log2e
  ca.src[4] = Wk;    ca.dst[4] = Wkb; ca.n8[4] = (int)(NW / 8);
  ca.src[5] = Wv;    ca.dst[5] = Wvb; ca.n8[5] = (int)(NW / 8);
  ca.src[6] = Wo;    ca.dst[6] = Wob; ca.n8[6] = (int)(NW / 8);

  cvt_bf16<<<dim3((unsigned)(NE / 8 / 256), 1, 7), dim3(256), 0, stream>>>(ca);
  proj_qkv<<<dim3(4, 16, 3), dim3(512), 0, stream>>>(
      Xq, Xk, Xv, Wqb, Wkb, Wvb, Q, K, Vt);
  flash_attn<<<dim3(NT * BATCH * HEADS), dim3(512), 0, stream>>>(Q, K, Vt, A);
  proj_out<<<dim3(D_MODEL / 64, M_ROWS / 128), dim3(256), 0, stream>>>(
      A, Wob, (float*)d_out);
}

// Round 25
// 106.478 us; speedup vs baseline: 1.1427x; 1.0187x over previous
//
#include <hip/hip_runtime.h>
#include <hip/hip_bf16.h>

// MultiheadAttention: out = (softmax_causal((Xq Wq^T)(Xk Wk^T)^T / 8) (Xv Wv^T)) Wo^T
// B=2 S=2048 D=1024 H=16 dk=64. bf16 MFMA (16x16x32), fp32 accum.
// R25: proj_out pipelined — double-buffered LDS + counted vmcnt(6) (kills
//      the per-iter vmcnt(0) drain hidden in __syncthreads) + XCD-pinned
//      block map (A panels L2-resident per XCD). cvt/proj_qkv/flash = R24.

typedef __attribute__((ext_vector_type(8))) __bf16 bf16x8;
typedef __attribute__((ext_vector_type(4))) __bf16 bf16x4;
typedef __attribute__((ext_vector_type(4))) float f32x4;

#define MFMA16(a, b, c) __builtin_amdgcn_mfma_f32_16x16x32_bf16((a), (b), (c), 0, 0, 0)

constexpr int D_MODEL = 1024;
constexpr int HEADS   = 16;
constexpr int DKH     = 64;
constexpr int BATCH   = 2;
constexpr int SEQ     = 2048;
constexpr int M_ROWS  = BATCH * SEQ;  // 4096
constexpr int QB = 64, KB = 64, NT = SEQ / QB;  // 32 q-tiles

typedef const unsigned int __attribute__((address_space(1)))* gas_u32;
typedef unsigned int __attribute__((address_space(3)))* las_u32;

// ---------------------------------------------------------------------------
// fp32 -> bf16 convert; seg 3 (Wq) pre-scaled by 0.125*log2(e) (exp2 softmax).
// Segs 0-5 granule-swizzled for the 8-phase GEMM staging (rule #21).
// ---------------------------------------------------------------------------
struct CvtArgs {
  const float* src[7];
  __bf16* dst[7];
  int n8[7];
};

__global__ __launch_bounds__(256) void cvt_bf16(CvtArgs a) {
  const int z = blockIdx.z;
  const int i = blockIdx.x * 256 + threadIdx.x;
  if (i >= a.n8[z]) return;
  const float sc = (z == 3) ? 0.18033688011112042f : 1.0f;  // 0.125*log2e
  const float4* s = (const float4*)a.src[z] + (size_t)i * 2;
  float4 x = s[0], y = s[1];
  bf16x8 o = {(__bf16)(x.x * sc), (__bf16)(x.y * sc), (__bf16)(x.z * sc), (__bf16)(x.w * sc),
              (__bf16)(y.x * sc), (__bf16)(y.y * sc), (__bf16)(y.z * sc), (__bf16)(y.w * sc)};
  size_t oi = (size_t)i;
  if (z < 6) {
    const int row = i >> 7;  // 1024 elems = 128 granules per row
    oi = (size_t)((i & ~7) | ((i & 7) ^ (row & 7)));
  }
  *(bf16x8*)(a.dst[z] + oi * 8) = o;
}

// ---------------------------------------------------------------------------
// 8-phase 256x256 GEMM (R19 schedule: 3-half-tile slack, vmcnt(6)/(4))
// ---------------------------------------------------------------------------
__global__ __launch_bounds__(512, 2) void proj_qkv(
    const __bf16* __restrict__ Xq, const __bf16* __restrict__ Xk,
    const __bf16* __restrict__ Xv, const __bf16* __restrict__ Wq,
    const __bf16* __restrict__ Wk, const __bf16* __restrict__ Wv,
    __bf16* __restrict__ Q, __bf16* __restrict__ K, __bf16* __restrict__ Vt) {
  __shared__ alignas(16) __bf16 As[2 * 256 * 64];  // 64 KB
  __shared__ alignas(16) __bf16 Bs[2 * 256 * 64];  // 64 KB

  int f = (blockIdx.z * gridDim.y + blockIdx.y) * gridDim.x + blockIdx.x;
  f = (f & 7) * 24 + (f >> 3);
  const int bx = f & 3, by = (f >> 2) & 15, bz = f >> 6;

  const __bf16* Ag; const __bf16* Bg;
  if (bz == 0)      { Ag = Xq; Bg = Wq; }
  else if (bz == 1) { Ag = Xk; Bg = Wk; }
  else              { Ag = Xv; Bg = Wv; }

  const int bm = by * 256, bn = bx * 256;
  const int tid = threadIdx.x, ln = tid & 63, wv = tid >> 6;
  const int wr = wv >> 2, wc = wv & 3;
  const int fr = ln & 15, fg = ln >> 4;

  auto stageA = [&](int buf, int h, int t) {
    const int kt = t * 64;
#pragma unroll
    for (int l = 0; l < 2; ++l) {
      const int gbase = l * 512 + wv * 64;
      const int d = gbase + ln;
      const __bf16* src = Ag + (size_t)(bm + h * 128 + (d >> 3)) * 1024 + kt + (d & 7) * 8;
      __builtin_amdgcn_global_load_lds((gas_u32)src,
          (las_u32)(As + (size_t)(buf * 2048 + h * 1024 + gbase) * 8), 16, 0, 0);
    }
  };
  auto stageB = [&](int buf, int h, int t) {
    const int kt = t * 64;
#pragma unroll
    for (int l = 0; l < 2; ++l) {
      const int gbase = l * 512 + wv * 64;
      const int d = gbase + ln;
      const __bf16* src = Bg + (size_t)(bn + h * 128 + (d >> 3)) * 1024 + kt + (d & 7) * 8;
      __builtin_amdgcn_global_load_lds((gas_u32)src,
          (las_u32)(Bs + (size_t)(buf * 2048 + h * 1024 + gbase) * 8), 16, 0, 0);
    }
  };

  f32x4 acc[8][4];
#pragma unroll
  for (int m = 0; m < 8; ++m)
#pragma unroll
    for (int n = 0; n < 4; ++n) acc[m][n] = (f32x4){0.f, 0.f, 0.f, 0.f};

  bf16x8 ra[4][2], rb[4][2];

  auto loadA = [&](int buf, int mbase) {
#pragma unroll
    for (int m = 0; m < 4; ++m)
#pragma unroll
      for (int kk = 0; kk < 2; ++kk) {
        const int row = wr * 128 + (mbase + m) * 16 + fr;
        ra[m][kk] = *(const bf16x8*)&As[(buf * 256 + row) * 64 +
                                        (((kk * 4 + fg) ^ (row & 7)) << 3)];
      }
  };
  auto loadB = [&](int buf, int n0) {
#pragma unroll
    for (int n = 0; n < 2; ++n)
#pragma unroll
      for (int kk = 0; kk < 2; ++kk) {
        const int row = wc * 64 + (n0 + n) * 16 + fr;
        rb[n0 + n][kk] = *(const bf16x8*)&Bs[(buf * 256 + row) * 64 +
                                             (((kk * 4 + fg) ^ (row & 7)) << 3)];
      }
  };
  auto quad = [&](int mb, int nb) {
    __builtin_amdgcn_s_setprio(1);
#pragma unroll
    for (int m = 0; m < 4; ++m)
#pragma unroll
      for (int n = 0; n < 2; ++n) {
        acc[mb + m][nb + n] = MFMA16(ra[m][0], rb[nb + n][0], acc[mb + m][nb + n]);
        acc[mb + m][nb + n] = MFMA16(ra[m][1], rb[nb + n][1], acc[mb + m][nb + n]);
      }
    __builtin_amdgcn_s_setprio(0);
  };

  stageB(0, 0, 0); stageB(0, 1, 0); stageA(0, 0, 0); stageA(0, 1, 0);
  stageB(1, 0, 1); stageA(1, 0, 1);
  asm volatile("s_waitcnt vmcnt(4)" ::: "memory");
  __builtin_amdgcn_s_barrier();

#pragma unroll 1
  for (int it = 0; it < 8; ++it) {
    const int T0 = 2 * it, T1 = 2 * it + 1;
    const bool nl = (it < 7);

    loadA(0, 0); loadB(0, 0); loadB(0, 2);
    stageB(1, 1, T1);
    __builtin_amdgcn_s_barrier();
    quad(0, 0);
    __builtin_amdgcn_s_barrier();

    stageA(1, 1, T1);
    if (nl) stageB(0, 0, T0 + 2);
    __builtin_amdgcn_s_barrier();
    quad(0, 2);
    __builtin_amdgcn_s_barrier();

    loadA(0, 4);
    if (nl) stageB(0, 1, T0 + 2);
    __builtin_amdgcn_s_barrier();
    quad(4, 0);
    __builtin_amdgcn_s_barrier();

    if (nl) {
      stageA(0, 0, T0 + 2);
      asm volatile("s_waitcnt vmcnt(6)" ::: "memory");
    } else {
      asm volatile("s_waitcnt vmcnt(0)" ::: "memory");
    }
    __builtin_amdgcn_s_barrier();
    quad(4, 2);
    __builtin_amdgcn_s_barrier();

    loadA(1, 0); loadB(1, 0); loadB(1, 2);
    if (nl) stageA(0, 1, T0 + 2);
    __builtin_amdgcn_s_barrier();
    quad(0, 0);
    __builtin_amdgcn_s_barrier();

    if (nl) stageB(1, 0, T1 + 2);
    __builtin_amdgcn_s_barrier();
    quad(0, 2);
    __builtin_amdgcn_s_barrier();

    loadA(1, 4);
    __builtin_amdgcn_s_barrier();
    quad(4, 0);
    __builtin_amdgcn_s_barrier();

    if (nl) {
      stageA(1, 0, T1 + 2);
      asm volatile("s_waitcnt vmcnt(4)" ::: "memory");
    }
    __builtin_amdgcn_s_barrier();
    quad(4, 2);
    __builtin_amdgcn_s_barrier();
  }

  if (bz == 2) {
    const int b = bm >> 11;
#pragma unroll
    for (int m = 0; m < 8; ++m)
#pragma unroll
      for (int n = 0; n < 4; ++n) {
        const int col = bn + wc * 64 + n * 16 + fr;
        const int s0  = (bm + wr * 128 + m * 16 + fg * 4) & (SEQ - 1);
        bf16x4 o = {(__bf16)acc[m][n][0], (__bf16)acc[m][n][1],
                    (__bf16)acc[m][n][2], (__bf16)acc[m][n][3]};
        *(bf16x4*)(Vt + (((size_t)(b * 1024 + col)) << 11) + s0) = o;
      }
  } else {
    __bf16* C = (bz == 0) ? Q : K;
#pragma unroll
    for (int m = 0; m < 8; ++m)
#pragma unroll
      for (int n = 0; n < 4; ++n)
#pragma unroll
        for (int r = 0; r < 4; ++r) {
          const int row = bm + wr * 128 + m * 16 + fg * 4 + r;
          const int col = bn + wc * 64 + n * 16 + fr;
          C[(size_t)row * 1024 + col] = (__bf16)acc[m][n][r];
        }
  }
}

// ---------------------------------------------------------------------------
// proj_out: 128x64 tile, DOUBLE-BUFFERED (counted vmcnt(6), no per-iter
// drain) + XCD-pinned map (XCD x owns A row-panels {4x..4x+3}: per-XCD A
// working set 1MB < 4MB L2). LDS 48KB. Grid 512 linear.
// ---------------------------------------------------------------------------
__global__ __launch_bounds__(256) void proj_out(const __bf16* __restrict__ Aattn,
                                                const __bf16* __restrict__ Wo,
                                                float* __restrict__ Out) {
  __shared__ alignas(16) __bf16 As[2][128 * 64];  // 32 KB
  __shared__ alignas(16) __bf16 Bs[2][64 * 64];   // 16 KB

  // XCD map: x = f&7 owns by in {4x..4x+3}; w = f>>3: by = x*4+(w&3), bx = w>>2
  const int f = blockIdx.x;             // 0..511
  const int x = f & 7, w = f >> 3;
  const int by = x * 4 + (w & 3);       // 0..31
  const int bx = w >> 2;                // 0..15
  const int bm = by * 128, bn = bx * 64;

  const int tid = threadIdx.x, ln = tid & 63, wv = tid >> 6;
  const int wr = wv >> 1, wc = wv & 1;
  const int fr = ln & 15, fg = ln >> 4;

  // 6 global_load_lds per thread per tile (4 A-chunks + 2 B-chunks)
  auto stage = [&](int buf, int t) {
    const int kt = t * 64;
#pragma unroll
    for (int i = 0; i < 4; ++i) {  // A: 16 chunks of 1KB
      const int c = wv * 4 + i;
      const int byte = c * 1024 + ln * 16;
      const int row = byte >> 7;
      const int col = (byte & 127) >> 1;
      const __bf16* ga = Aattn + (size_t)(bm + row) * 1024 + kt + col;
      __builtin_amdgcn_global_load_lds((gas_u32)ga, (las_u32)(&As[buf][c * 512]),
                                       16, 0, 0);
    }
#pragma unroll
    for (int i = 0; i < 2; ++i) {  // B: 8 chunks of 1KB
      const int c = wv * 2 + i;
      const int byte = c * 1024 + ln * 16;
      const int row = byte >> 7;
      const int col = (byte & 127) >> 1;
      const __bf16* gb = Wo + (size_t)(bn + row) * 1024 + kt + col;
      __builtin_amdgcn_global_load_lds((gas_u32)gb, (las_u32)(&Bs[buf][c * 512]),
                                       16, 0, 0);
    }
  };

  f32x4 acc[4][2];
#pragma unroll
  for (int m = 0; m < 4; ++m)
#pragma unroll
    for (int n = 0; n < 2; ++n) acc[m][n] = (f32x4){0.f, 0.f, 0.f, 0.f};

  stage(0, 0);

#pragma unroll 1
  for (int t = 0; t < 16; ++t) {
    const int cur = t & 1;
    // stage tile t+1 into buf cur^1: its readers (iter t-1) finished at the
    // trailing barrier of iter t-1, which precedes this point.
    if (t + 1 < 16) {
      stage(cur ^ 1, t + 1);
      asm volatile("s_waitcnt vmcnt(6)" ::: "memory");  // tile t landed
    } else {
      asm volatile("s_waitcnt vmcnt(0)" ::: "memory");
    }
    __builtin_amdgcn_s_barrier();

#pragma unroll
    for (int kk = 0; kk < 2; ++kk) {
      const int kc = kk * 32 + fg * 8;
      bf16x8 af[4], bfv[2];
#pragma unroll
      for (int m = 0; m < 4; ++m)
        af[m] = *(const bf16x8*)&As[cur][(wr * 64 + m * 16 + fr) * 64 + kc];
#pragma unroll
      for (int n = 0; n < 2; ++n)
        bfv[n] = *(const bf16x8*)&Bs[cur][(wc * 32 + n * 16 + fr) * 64 + kc];
#pragma unroll
      for (int m = 0; m < 4; ++m)
#pragma unroll
        for (int n = 0; n < 2; ++n) acc[m][n] = MFMA16(af[m], bfv[n], acc[m][n]);
    }
    __builtin_amdgcn_s_barrier();  // protect buf cur from next iter's stage
  }

#pragma unroll
  for (int m = 0; m < 4; ++m)
#pragma unroll
    for (int n = 0; n < 2; ++n)
#pragma unroll
      for (int r = 0; r < 4; ++r) {
        const int row = bm + wr * 64 + m * 16 + fg * 4 + r;
        const int col = bn + wc * 32 + n * 16 + fr;
        Out[(size_t)row * 1024 + col] = acc[m][n][r];
      }
}

// ---------------------------------------------------------------------------
// Flash attention, causal, KV-split + XCD pinning (R24, unchanged).
// ---------------------------------------------------------------------------
__device__ __forceinline__ int SWZ(int row, int col) {
  return row * 64 + (col ^ ((row & 7) << 3));
}

__global__ __launch_bounds__(512, 2) void flash_attn(
    const __bf16* __restrict__ Q, const __bf16* __restrict__ K,
    const __bf16* __restrict__ Vt, __bf16* __restrict__ O) {
  __shared__ alignas(16) __bf16 Ks[2][2][64 * 64];  // [grp][buf] 32 KB
  __shared__ alignas(16) __bf16 Vs[2][2][64 * 64];  // 32 KB
  __shared__ alignas(16) __bf16 Ps[8][16 * 64];     // 16 KB (reused: merge acc)

  const int f  = blockIdx.x;            // 0..1023
  const int x  = f & 7, w = f >> 3;     // w 0..127
  const int qt = 31 - (w >> 2);         // longest first
  const int bh = x * 4 + (w & 3);
  const int b  = bh >> 4;
  const int h  = bh & 15;

  const int tid  = threadIdx.x;
  const int lane = tid & 63, wave = tid >> 6;
  const int grp = wave >> 2, wg = wave & 3;  // group / wave-in-group
  const int fr = lane & 15, fg = lane >> 4;

  const int len = qt + 1;
  const int h0  = (len + 1) >> 1;       // grp0 [0,h0), grp1 [h0,len)
  const int t0  = grp ? h0 : 0;
  const int tlast = grp ? len : h0;     // exclusive end of this grp's range

  const __bf16* Kh = K + (size_t)b * SEQ * D_MODEL + h * DKH;
  const __bf16* Vh = Vt + (size_t)(bh * DKH) * SEQ;

  auto stage = [&](int buf, int t) {
#pragma unroll
    for (int p = 0; p < 2; ++p) {
      const int row = p * 32 + wg * 8 + (lane >> 3);
      const int sg  = (lane & 7) ^ (row & 7);
      const __bf16* ks = Kh + (size_t)(t * KB + row) * D_MODEL + sg * 8;
      __builtin_amdgcn_global_load_lds((gas_u32)ks,
          (las_u32)(&Ks[grp][buf][(size_t)(p * 256 + wg * 64) * 8]), 16, 0, 0);
      const __bf16* vs = Vh + (size_t)row * SEQ + t * KB + sg * 8;
      __builtin_amdgcn_global_load_lds((gas_u32)vs,
          (las_u32)(&Vs[grp][buf][(size_t)(p * 256 + wg * 64) * 8]), 16, 0, 0);
    }
  };

  f32x4 acc[4];
#pragma unroll
  for (int n = 0; n < 4; ++n) acc[n] = (f32x4){0.f, 0.f, 0.f, 0.f};
  f32x4 l4 = (f32x4){0.f, 0.f, 0.f, 0.f};

  bf16x8 q0, q1;
  {
    const size_t qrow = (size_t)(b * SEQ + qt * QB + wg * 16 + fr) * D_MODEL + h * DKH;
    q0 = *(const bf16x8*)(Q + qrow + fg * 8);
    q1 = *(const bf16x8*)(Q + qrow + 32 + fg * 8);
  }

  const bf16x8 ones = {(__bf16)1.f, (__bf16)1.f, (__bf16)1.f, (__bf16)1.f,
                       (__bf16)1.f, (__bf16)1.f, (__bf16)1.f, (__bf16)1.f};

  auto step = [&](const int t, const int cur, __bf16* __restrict__ ps) {
    f32x4 s[4];
    __builtin_amdgcn_s_setprio(1);
#pragma unroll
    for (int kb = 0; kb < 4; ++kb) {
      f32x4 a = (f32x4){0.f, 0.f, 0.f, 0.f};
      bf16x8 kf0 = *(const bf16x8*)&Ks[grp][cur][SWZ(kb * 16 + fr, fg * 8)];
      bf16x8 kf1 = *(const bf16x8*)&Ks[grp][cur][SWZ(kb * 16 + fr, 32 + fg * 8)];
      a = MFMA16(kf0, q0, a);
      a = MFMA16(kf1, q1, a);
      s[kb] = a;
    }
    __builtin_amdgcn_s_setprio(0);

    if (t == qt) {  // causal mask, lane-local (diagonal KV tile)
      const int qin = wg * 16 + fr;
#pragma unroll
      for (int kb = 0; kb < 4; ++kb)
#pragma unroll
        for (int r = 0; r < 4; ++r)
          if (kb * 16 + fg * 4 + r > qin) s[kb][r] = -INFINITY;
    }

#pragma unroll
    for (int kb = 0; kb < 4; ++kb) {
      bf16x4 wv = {(__bf16)__builtin_amdgcn_exp2f(s[kb][0]),
                   (__bf16)__builtin_amdgcn_exp2f(s[kb][1]),
                   (__bf16)__builtin_amdgcn_exp2f(s[kb][2]),
                   (__bf16)__builtin_amdgcn_exp2f(s[kb][3])};
      *(bf16x4*)&ps[SWZ(fr, kb * 16 + fg * 4)] = wv;
    }

    __builtin_amdgcn_s_setprio(1);
#pragma unroll
    for (int k2 = 0; k2 < 2; ++k2) {
      bf16x8 pf = *(const bf16x8*)&ps[SWZ(fr, k2 * 32 + fg * 8)];
#pragma unroll
      for (int n = 0; n < 4; ++n) {
        bf16x8 vf = *(const bf16x8*)&Vs[grp][cur][SWZ(n * 16 + fr, k2 * 32 + fg * 8)];
        acc[n] = MFMA16(pf, vf, acc[n]);
      }
      l4 = MFMA16(pf, ones, l4);
    }
    __builtin_amdgcn_s_setprio(0);
  };

  stage(0, t0);
  asm volatile("s_waitcnt vmcnt(0)" ::: "memory");
  __syncthreads();

#pragma unroll 1
  for (int i = 0; i < h0; ++i) {
    const int t = t0 + i;
    const int cur = i & 1;

    if (t + 1 < tlast) stage(cur ^ 1, t + 1);  // latency hides under step
    if (t < tlast) step(t, cur, &Ps[wave][0]);

    asm volatile("s_waitcnt vmcnt(0)" ::: "memory");
    __syncthreads();
  }

  // ---- merge (m=0): O = (acc0 + acc1) / (l0 + l1) ----
  float* accb = (float*)&Ps[0][0];        // 4 waves x 16 x 64 f32 = 16 KB
  float* lb   = (float*)&Ks[0][0][0];     // 4 KB scratch (grp0 buf0, done)
  if (grp == 1) {
#pragma unroll
    for (int n = 0; n < 4; ++n)
#pragma unroll
      for (int r = 0; r < 4; ++r)
        accb[(wg * 16 + n * 4 + r) * 64 + lane] = acc[n][r];
#pragma unroll
    for (int r = 0; r < 4; ++r) lb[(wg * 4 + r) * 64 + lane] = l4[r];
  }
  __syncthreads();
  if (grp == 0) {
#pragma unroll
    for (int n = 0; n < 4; ++n)
#pragma unroll
      for (int r = 0; r < 4; ++r) acc[n][r] += accb[(wg * 16 + n * 4 + r) * 64 + lane];
#pragma unroll
    for (int r = 0; r < 4; ++r) l4[r] += lb[(wg * 4 + r) * 64 + lane];

    const size_t obase = (size_t)(b * SEQ + qt * QB + wg * 16) * D_MODEL + h * DKH;
#pragma unroll
    for (int n = 0; n < 4; ++n)
#pragma unroll
      for (int r = 0; r < 4; ++r) {
        const int row = fg * 4 + r;
        O[obase + (size_t)row * D_MODEL + n * 16 + fr] =
            (__bf16)(acc[n][r] / l4[r]);
      }
  }
}

// ---------------------------------------------------------------------------
extern "C" void kernel_launch(void* const* d_in, const int* in_sizes, int n_in,
                              void* d_out, int out_size, void* d_ws, size_t ws_size,
                              hipStream_t stream) {
  const float* q_src = (const float*)d_in[0];
  const float* k_src = (const float*)d_in[1];
  const float* v_src = (const float*)d_in[2];
  // d_in[3] = causal tril mask (fixed) -> applied analytically
  const float* Wq = (const float*)d_in[4];
  const float* Wk = (const float*)d_in[5];
  const float* Wv = (const float*)d_in[6];
  const float* Wo = (const float*)d_in[7];

  const size_t NE = (size_t)M_ROWS * D_MODEL;  // 4M elems
  const size_t NW = (size_t)D_MODEL * D_MODEL; // 1M elems
  __bf16* Xq  = (__bf16*)d_ws;
  __bf16* Xk  = Xq + NE;
  __bf16* Xv  = Xk + NE;
  __bf16* Wqb = Xv + NE;
  __bf16* Wkb = Wqb + NW;
  __bf16* Wvb = Wkb + NW;
  __bf16* Wob = Wvb + NW;
  __bf16* Q   = Wob + NW;
  __bf16* K   = Q + NE;
  __bf16* Vt  = K + NE;
  __bf16* A   = Xq;  // Xq consumed by proj_qkv before flash writes A

  CvtArgs ca;
  ca.src[0] = q_src; ca.dst[0] = Xq;  ca.n8[0] = (int)(NE / 8);
  ca.src[1] = k_src; ca.dst[1] = Xk;  ca.n8[1] = (int)(NE / 8);
  ca.src[2] = v_src; ca.dst[2] = Xv;  ca.n8[2] = (int)(NE / 8);
  ca.src[3] = Wq;    ca.dst[3] = Wqb; ca.n8[3] = (int)(NW / 8);  // x0.125*log2e
  ca.src[4] = Wk;    ca.dst[4] = Wkb; ca.n8[4] = (int)(NW / 8);
  ca.src[5] = Wv;    ca.dst[5] = Wvb; ca.n8[5] = (int)(NW / 8);
  ca.src[6] = Wo;    ca.dst[6] = Wob; ca.n8[6] = (int)(NW / 8);

  cvt_bf16<<<dim3((unsigned)(NE / 8 / 256), 1, 7), dim3(256), 0, stream>>>(ca);
  proj_qkv<<<dim3(4, 16, 3), dim3(512), 0, stream>>>(
      Xq, Xk, Xv, Wqb, Wkb, Wvb, Q, K, Vt);
  flash_attn<<<dim3(NT * BATCH * HEADS), dim3(512), 0, stream>>>(Q, K, Vt, A);
  proj_out<<<dim3(512), dim3(256), 0, stream>>>(A, Wob, (float*)d_out);
}

// Round 26
// 106.001 us; speedup vs baseline: 1.1479x; 1.0045x over previous
//
#include <hip/hip_runtime.h>
#include <hip/hip_bf16.h>

// MultiheadAttention: out = (softmax_causal((Xq Wq^T)(Xk Wk^T)^T / 8) (Xv Wv^T)) Wo^T
// B=2 S=2048 D=1024 H=16 dk=64. bf16 MFMA (16x16x32), fp32 accum.
// R26: proj_qkv retiled 256^2 -> 128^2 in the R25-proven dbuf+counted-vmcnt
//      structure: grid 768 = 3 FULL rounds of 256 CUs (was 192 = 75% fill,
//      the kernel's binding constraint). 4 waves, wave tile 64x64, LDS 64KB
//      (2 blocks/CU), vmcnt(8) steady, XCD-pinned A panels.
//      cvt/flash/proj_out = R25.

typedef __attribute__((ext_vector_type(8))) __bf16 bf16x8;
typedef __attribute__((ext_vector_type(4))) __bf16 bf16x4;
typedef __attribute__((ext_vector_type(4))) float f32x4;

#define MFMA16(a, b, c) __builtin_amdgcn_mfma_f32_16x16x32_bf16((a), (b), (c), 0, 0, 0)

constexpr int D_MODEL = 1024;
constexpr int HEADS   = 16;
constexpr int DKH     = 64;
constexpr int BATCH   = 2;
constexpr int SEQ     = 2048;
constexpr int M_ROWS  = BATCH * SEQ;  // 4096
constexpr int QB = 64, KB = 64, NT = SEQ / QB;  // 32 q-tiles

typedef const unsigned int __attribute__((address_space(1)))* gas_u32;
typedef unsigned int __attribute__((address_space(3)))* las_u32;

// ---------------------------------------------------------------------------
// fp32 -> bf16 convert; seg 3 (Wq) pre-scaled by 0.125*log2(e) (exp2 softmax).
// Segs 0-5 granule-swizzled for the GEMM staging (rule #21).
// ---------------------------------------------------------------------------
struct CvtArgs {
  const float* src[7];
  __bf16* dst[7];
  int n8[7];
};

__global__ __launch_bounds__(256) void cvt_bf16(CvtArgs a) {
  const int z = blockIdx.z;
  const int i = blockIdx.x * 256 + threadIdx.x;
  if (i >= a.n8[z]) return;
  const float sc = (z == 3) ? 0.18033688011112042f : 1.0f;  // 0.125*log2e
  const float4* s = (const float4*)a.src[z] + (size_t)i * 2;
  float4 x = s[0], y = s[1];
  bf16x8 o = {(__bf16)(x.x * sc), (__bf16)(x.y * sc), (__bf16)(x.z * sc), (__bf16)(x.w * sc),
              (__bf16)(y.x * sc), (__bf16)(y.y * sc), (__bf16)(y.z * sc), (__bf16)(y.w * sc)};
  size_t oi = (size_t)i;
  if (z < 6) {
    const int row = i >> 7;  // 1024 elems = 128 granules per row
    oi = (size_t)((i & ~7) | ((i & 7) ^ (row & 7)));
  }
  *(bf16x8*)(a.dst[z] + oi * 8) = o;
}

// ---------------------------------------------------------------------------
// proj_qkv: 128x128 tile, double-buffered, counted vmcnt(8). Grid 768
// (= 3 full rounds of 256 CUs). 4 waves 2x2, wave tile 64x64, acc[4][4].
// XCD map: x = f&7 owns A row-panels {4x..4x+3} per z.
// ---------------------------------------------------------------------------
__global__ __launch_bounds__(256) void proj_qkv(
    const __bf16* __restrict__ Xq, const __bf16* __restrict__ Xk,
    const __bf16* __restrict__ Xv, const __bf16* __restrict__ Wq,
    const __bf16* __restrict__ Wk, const __bf16* __restrict__ Wv,
    __bf16* __restrict__ Q, __bf16* __restrict__ K, __bf16* __restrict__ Vt) {
  __shared__ alignas(16) __bf16 As[2][128 * 64];  // 32 KB
  __shared__ alignas(16) __bf16 Bs[2][128 * 64];  // 32 KB

  // f = 0..767; x = f&7 (dispatch XCD); w = f>>3 (0..95):
  // bz = w/32, rem = w%32, by = x*4 + (rem&3) (0..31), bx = rem>>2 (0..7)
  const int f = blockIdx.x;
  const int x = f & 7, w = f >> 3;
  const int bz = w >> 5, rem = w & 31;
  const int by = x * 4 + (rem & 3);
  const int bx = rem >> 2;

  const __bf16* Ag; const __bf16* Bg;
  if (bz == 0)      { Ag = Xq; Bg = Wq; }
  else if (bz == 1) { Ag = Xk; Bg = Wk; }
  else              { Ag = Xv; Bg = Wv; }

  const int bm = by * 128, bn = bx * 128;
  const int tid = threadIdx.x, ln = tid & 63, wv = tid >> 6;
  const int wr = wv >> 1, wc = wv & 1;       // 2x2 wave grid, 64x64 tile
  const int fr = ln & 15, fg = ln >> 4;

  // stage one 128x64 A-tile + 128x64 B-tile (16 chunks of 1KB each);
  // 4 chunks/wave each -> 8 global_load_lds per thread per tile.
  auto stage = [&](int buf, int t) {
    const int kt = t * 64;
#pragma unroll
    for (int i = 0; i < 4; ++i) {
      const int c = wv * 4 + i;
      const int byte = c * 1024 + ln * 16;
      const int row = byte >> 7;
      const int col = (byte & 127) >> 1;
      const __bf16* ga = Ag + (size_t)(bm + row) * 1024 + kt + col;
      __builtin_amdgcn_global_load_lds((gas_u32)ga, (las_u32)(&As[buf][c * 512]),
                                       16, 0, 0);
      const __bf16* gb = Bg + (size_t)(bn + row) * 1024 + kt + col;
      __builtin_amdgcn_global_load_lds((gas_u32)gb, (las_u32)(&Bs[buf][c * 512]),
                                       16, 0, 0);
    }
  };

  f32x4 acc[4][4];
#pragma unroll
  for (int m = 0; m < 4; ++m)
#pragma unroll
    for (int n = 0; n < 4; ++n) acc[m][n] = (f32x4){0.f, 0.f, 0.f, 0.f};

  stage(0, 0);

#pragma unroll 1
  for (int t = 0; t < 16; ++t) {
    const int cur = t & 1;
    // stage t+1 into buf cur^1 (readers finished at iter t-1's trailing
    // barrier); newest 8 outstanding = tile t+1 -> vmcnt(8) proves t landed.
    if (t + 1 < 16) {
      stage(cur ^ 1, t + 1);
      asm volatile("s_waitcnt vmcnt(8)" ::: "memory");
    } else {
      asm volatile("s_waitcnt vmcnt(0)" ::: "memory");
    }
    __builtin_amdgcn_s_barrier();

#pragma unroll
    for (int kk = 0; kk < 2; ++kk) {
      bf16x8 af[4], bfv[4];
#pragma unroll
      for (int m = 0; m < 4; ++m) {
        const int row = wr * 64 + m * 16 + fr;
        af[m] = *(const bf16x8*)&As[cur][row * 64 + (((kk * 4 + fg) ^ (row & 7)) << 3)];
      }
#pragma unroll
      for (int n = 0; n < 4; ++n) {
        const int row = wc * 64 + n * 16 + fr;
        bfv[n] = *(const bf16x8*)&Bs[cur][row * 64 + (((kk * 4 + fg) ^ (row & 7)) << 3)];
      }
      __builtin_amdgcn_s_setprio(1);
#pragma unroll
      for (int m = 0; m < 4; ++m)
#pragma unroll
        for (int n = 0; n < 4; ++n) acc[m][n] = MFMA16(af[m], bfv[n], acc[m][n]);
      __builtin_amdgcn_s_setprio(0);
    }
    __builtin_amdgcn_s_barrier();  // protect buf cur from next iter's stage
  }

  if (bz == 2) {
    // Vt[(b*1024 + col)][s]: per frag 4 contiguous s at fixed col
    const int b = bm >> 11;
#pragma unroll
    for (int m = 0; m < 4; ++m)
#pragma unroll
      for (int n = 0; n < 4; ++n) {
        const int col = bn + wc * 64 + n * 16 + fr;
        const int s0  = (bm + wr * 64 + m * 16 + fg * 4) & (SEQ - 1);
        bf16x4 o = {(__bf16)acc[m][n][0], (__bf16)acc[m][n][1],
                    (__bf16)acc[m][n][2], (__bf16)acc[m][n][3]};
        *(bf16x4*)(Vt + (((size_t)(b * 1024 + col)) << 11) + s0) = o;
      }
  } else {
    __bf16* C = (bz == 0) ? Q : K;
#pragma unroll
    for (int m = 0; m < 4; ++m)
#pragma unroll
      for (int n = 0; n < 4; ++n)
#pragma unroll
        for (int r = 0; r < 4; ++r) {
          const int row = bm + wr * 64 + m * 16 + fg * 4 + r;
          const int col = bn + wc * 64 + n * 16 + fr;
          C[(size_t)row * 1024 + col] = (__bf16)acc[m][n][r];
        }
  }
}

// ---------------------------------------------------------------------------
// proj_out: 128x64 tile, double-buffered, counted vmcnt(6), XCD-pinned map
// (R25, unchanged).
// ---------------------------------------------------------------------------
__global__ __launch_bounds__(256) void proj_out(const __bf16* __restrict__ Aattn,
                                                const __bf16* __restrict__ Wo,
                                                float* __restrict__ Out) {
  __shared__ alignas(16) __bf16 As[2][128 * 64];  // 32 KB
  __shared__ alignas(16) __bf16 Bs[2][64 * 64];   // 16 KB

  const int f = blockIdx.x;             // 0..511
  const int x = f & 7, w = f >> 3;
  const int by = x * 4 + (w & 3);       // 0..31
  const int bx = w >> 2;                // 0..15
  const int bm = by * 128, bn = bx * 64;

  const int tid = threadIdx.x, ln = tid & 63, wv = tid >> 6;
  const int wr = wv >> 1, wc = wv & 1;
  const int fr = ln & 15, fg = ln >> 4;

  auto stage = [&](int buf, int t) {
    const int kt = t * 64;
#pragma unroll
    for (int i = 0; i < 4; ++i) {  // A: 16 chunks of 1KB
      const int c = wv * 4 + i;
      const int byte = c * 1024 + ln * 16;
      const int row = byte >> 7;
      const int col = (byte & 127) >> 1;
      const __bf16* ga = Aattn + (size_t)(bm + row) * 1024 + kt + col;
      __builtin_amdgcn_global_load_lds((gas_u32)ga, (las_u32)(&As[buf][c * 512]),
                                       16, 0, 0);
    }
#pragma unroll
    for (int i = 0; i < 2; ++i) {  // B: 8 chunks of 1KB
      const int c = wv * 2 + i;
      const int byte = c * 1024 + ln * 16;
      const int row = byte >> 7;
      const int col = (byte & 127) >> 1;
      const __bf16* gb = Wo + (size_t)(bn + row) * 1024 + kt + col;
      __builtin_amdgcn_global_load_lds((gas_u32)gb, (las_u32)(&Bs[buf][c * 512]),
                                       16, 0, 0);
    }
  };

  f32x4 acc[4][2];
#pragma unroll
  for (int m = 0; m < 4; ++m)
#pragma unroll
    for (int n = 0; n < 2; ++n) acc[m][n] = (f32x4){0.f, 0.f, 0.f, 0.f};

  stage(0, 0);

#pragma unroll 1
  for (int t = 0; t < 16; ++t) {
    const int cur = t & 1;
    if (t + 1 < 16) {
      stage(cur ^ 1, t + 1);
      asm volatile("s_waitcnt vmcnt(6)" ::: "memory");  // tile t landed
    } else {
      asm volatile("s_waitcnt vmcnt(0)" ::: "memory");
    }
    __builtin_amdgcn_s_barrier();

#pragma unroll
    for (int kk = 0; kk < 2; ++kk) {
      const int kc = kk * 32 + fg * 8;
      bf16x8 af[4], bfv[2];
#pragma unroll
      for (int m = 0; m < 4; ++m)
        af[m] = *(const bf16x8*)&As[cur][(wr * 64 + m * 16 + fr) * 64 + kc];
#pragma unroll
      for (int n = 0; n < 2; ++n)
        bfv[n] = *(const bf16x8*)&Bs[cur][(wc * 32 + n * 16 + fr) * 64 + kc];
#pragma unroll
      for (int m = 0; m < 4; ++m)
#pragma unroll
        for (int n = 0; n < 2; ++n) acc[m][n] = MFMA16(af[m], bfv[n], acc[m][n]);
    }
    __builtin_amdgcn_s_barrier();
  }

#pragma unroll
  for (int m = 0; m < 4; ++m)
#pragma unroll
    for (int n = 0; n < 2; ++n)
#pragma unroll
      for (int r = 0; r < 4; ++r) {
        const int row = bm + wr * 64 + m * 16 + fg * 4 + r;
        const int col = bn + wc * 32 + n * 16 + fr;
        Out[(size_t)row * 1024 + col] = acc[m][n][r];
      }
}

// ---------------------------------------------------------------------------
// Flash attention, causal, KV-split + XCD pinning (R24, unchanged).
// ---------------------------------------------------------------------------
__device__ __forceinline__ int SWZ(int row, int col) {
  return row * 64 + (col ^ ((row & 7) << 3));
}

__global__ __launch_bounds__(512, 2) void flash_attn(
    const __bf16* __restrict__ Q, const __bf16* __restrict__ K,
    const __bf16* __restrict__ Vt, __bf16* __restrict__ O) {
  __shared__ alignas(16) __bf16 Ks[2][2][64 * 64];  // [grp][buf] 32 KB
  __shared__ alignas(16) __bf16 Vs[2][2][64 * 64];  // 32 KB
  __shared__ alignas(16) __bf16 Ps[8][16 * 64];     // 16 KB (reused: merge acc)

  const int f  = blockIdx.x;            // 0..1023
  const int x  = f & 7, w = f >> 3;     // w 0..127
  const int qt = 31 - (w >> 2);         // longest first
  const int bh = x * 4 + (w & 3);
  const int b  = bh >> 4;
  const int h  = bh & 15;

  const int tid  = threadIdx.x;
  const int lane = tid & 63, wave = tid >> 6;
  const int grp = wave >> 2, wg = wave & 3;  // group / wave-in-group
  const int fr = lane & 15, fg = lane >> 4;

  const int len = qt + 1;
  const int h0  = (len + 1) >> 1;       // grp0 [0,h0), grp1 [h0,len)
  const int t0  = grp ? h0 : 0;
  const int tlast = grp ? len : h0;     // exclusive end of this grp's range

  const __bf16* Kh = K + (size_t)b * SEQ * D_MODEL + h * DKH;
  const __bf16* Vh = Vt + (size_t)(bh * DKH) * SEQ;

  auto stage = [&](int buf, int t) {
#pragma unroll
    for (int p = 0; p < 2; ++p) {
      const int row = p * 32 + wg * 8 + (lane >> 3);
      const int sg  = (lane & 7) ^ (row & 7);
      const __bf16* ks = Kh + (size_t)(t * KB + row) * D_MODEL + sg * 8;
      __builtin_amdgcn_global_load_lds((gas_u32)ks,
          (las_u32)(&Ks[grp][buf][(size_t)(p * 256 + wg * 64) * 8]), 16, 0, 0);
      const __bf16* vs = Vh + (size_t)row * SEQ + t * KB + sg * 8;
      __builtin_amdgcn_global_load_lds((gas_u32)vs,
          (las_u32)(&Vs[grp][buf][(size_t)(p * 256 + wg * 64) * 8]), 16, 0, 0);
    }
  };

  f32x4 acc[4];
#pragma unroll
  for (int n = 0; n < 4; ++n) acc[n] = (f32x4){0.f, 0.f, 0.f, 0.f};
  f32x4 l4 = (f32x4){0.f, 0.f, 0.f, 0.f};

  bf16x8 q0, q1;
  {
    const size_t qrow = (size_t)(b * SEQ + qt * QB + wg * 16 + fr) * D_MODEL + h * DKH;
    q0 = *(const bf16x8*)(Q + qrow + fg * 8);
    q1 = *(const bf16x8*)(Q + qrow + 32 + fg * 8);
  }

  const bf16x8 ones = {(__bf16)1.f, (__bf16)1.f, (__bf16)1.f, (__bf16)1.f,
                       (__bf16)1.f, (__bf16)1.f, (__bf16)1.f, (__bf16)1.f};

  auto step = [&](const int t, const int cur, __bf16* __restrict__ ps) {
    f32x4 s[4];
    __builtin_amdgcn_s_setprio(1);
#pragma unroll
    for (int kb = 0; kb < 4; ++kb) {
      f32x4 a = (f32x4){0.f, 0.f, 0.f, 0.f};
      bf16x8 kf0 = *(const bf16x8*)&Ks[grp][cur][SWZ(kb * 16 + fr, fg * 8)];
      bf16x8 kf1 = *(const bf16x8*)&Ks[grp][cur][SWZ(kb * 16 + fr, 32 + fg * 8)];
      a = MFMA16(kf0, q0, a);
      a = MFMA16(kf1, q1, a);
      s[kb] = a;
    }
    __builtin_amdgcn_s_setprio(0);

    if (t == qt) {  // causal mask, lane-local (diagonal KV tile)
      const int qin = wg * 16 + fr;
#pragma unroll
      for (int kb = 0; kb < 4; ++kb)
#pragma unroll
        for (int r = 0; r < 4; ++r)
          if (kb * 16 + fg * 4 + r > qin) s[kb][r] = -INFINITY;
    }

#pragma unroll
    for (int kb = 0; kb < 4; ++kb) {
      bf16x4 wv = {(__bf16)__builtin_amdgcn_exp2f(s[kb][0]),
                   (__bf16)__builtin_amdgcn_exp2f(s[kb][1]),
                   (__bf16)__builtin_amdgcn_exp2f(s[kb][2]),
                   (__bf16)__builtin_amdgcn_exp2f(s[kb][3])};
      *(bf16x4*)&ps[SWZ(fr, kb * 16 + fg * 4)] = wv;
    }

    __builtin_amdgcn_s_setprio(1);
#pragma unroll
    for (int k2 = 0; k2 < 2; ++k2) {
      bf16x8 pf = *(const bf16x8*)&ps[SWZ(fr, k2 * 32 + fg * 8)];
#pragma unroll
      for (int n = 0; n < 4; ++n) {
        bf16x8 vf = *(const bf16x8*)&Vs[grp][cur][SWZ(n * 16 + fr, k2 * 32 + fg * 8)];
        acc[n] = MFMA16(pf, vf, acc[n]);
      }
      l4 = MFMA16(pf, ones, l4);
    }
    __builtin_amdgcn_s_setprio(0);
  };

  stage(0, t0);
  asm volatile("s_waitcnt vmcnt(0)" ::: "memory");
  __syncthreads();

#pragma unroll 1
  for (int i = 0; i < h0; ++i) {
    const int t = t0 + i;
    const int cur = i & 1;

    if (t + 1 < tlast) stage(cur ^ 1, t + 1);  // latency hides under step
    if (t < tlast) step(t, cur, &Ps[wave][0]);

    asm volatile("s_waitcnt vmcnt(0)" ::: "memory");
    __syncthreads();
  }

  // ---- merge (m=0): O = (acc0 + acc1) / (l0 + l1) ----
  float* accb = (float*)&Ps[0][0];        // 4 waves x 16 x 64 f32 = 16 KB
  float* lb   = (float*)&Ks[0][0][0];     // 4 KB scratch (grp0 buf0, done)
  if (grp == 1) {
#pragma unroll
    for (int n = 0; n < 4; ++n)
#pragma unroll
      for (int r = 0; r < 4; ++r)
        accb[(wg * 16 + n * 4 + r) * 64 + lane] = acc[n][r];
#pragma unroll
    for (int r = 0; r < 4; ++r) lb[(wg * 4 + r) * 64 + lane] = l4[r];
  }
  __syncthreads();
  if (grp == 0) {
#pragma unroll
    for (int n = 0; n < 4; ++n)
#pragma unroll
      for (int r = 0; r < 4; ++r) acc[n][r] += accb[(wg * 16 + n * 4 + r) * 64 + lane];
#pragma unroll
    for (int r = 0; r < 4; ++r) l4[r] += lb[(wg * 4 + r) * 64 + lane];

    const size_t obase = (size_t)(b * SEQ + qt * QB + wg * 16) * D_MODEL + h * DKH;
#pragma unroll
    for (int n = 0; n < 4; ++n)
#pragma unroll
      for (int r = 0; r < 4; ++r) {
        const int row = fg * 4 + r;
        O[obase + (size_t)row * D_MODEL + n * 16 + fr] =
            (__bf16)(acc[n][r] / l4[r]);
      }
  }
}

// ---------------------------------------------------------------------------
extern "C" void kernel_launch(void* const* d_in, const int* in_sizes, int n_in,
                              void* d_out, int out_size, void* d_ws, size_t ws_size,
                              hipStream_t stream) {
  const float* q_src = (const float*)d_in[0];
  const float* k_src = (const float*)d_in[1];
  const float* v_src = (const float*)d_in[2];
  // d_in[3] = causal tril mask (fixed) -> applied analytically
  const float* Wq = (const float*)d_in[4];
  const float* Wk = (const float*)d_in[5];
  const float* Wv = (const float*)d_in[6];
  const float* Wo = (const float*)d_in[7];

  const size_t NE = (size_t)M_ROWS * D_MODEL;  // 4M elems
  const size_t NW = (size_t)D_MODEL * D_MODEL; // 1M elems
  __bf16* Xq  = (__bf16*)d_ws;
  __bf16* Xk  = Xq + NE;
  __bf16* Xv  = Xk + NE;
  __bf16* Wqb = Xv + NE;
  __bf16* Wkb = Wqb + NW;
  __bf16* Wvb = Wkb + NW;
  __bf16* Wob = Wvb + NW;
  __bf16* Q   = Wob + NW;
  __bf16* K   = Q + NE;
  __bf16* Vt  = K + NE;
  __bf16* A   = Xq;  // Xq consumed by proj_qkv before flash writes A

  CvtArgs ca;
  ca.src[0] = q_src; ca.dst[0] = Xq;  ca.n8[0] = (int)(NE / 8);
  ca.src[1] = k_src; ca.dst[1] = Xk;  ca.n8[1] = (int)(NE / 8);
  ca.src[2] = v_src; ca.dst[2] = Xv;  ca.n8[2] = (int)(NE / 8);
  ca.src[3] = Wq;    ca.dst[3] = Wqb; ca.n8[3] = (int)(NW / 8);  // x0.125*log2e
  ca.src[4] = Wk;    ca.dst[4] = Wkb; ca.n8[4] = (int)(NW / 8);
  ca.src[5] = Wv;    ca.dst[5] = Wvb; ca.n8[5] = (int)(NW / 8);
  ca.src[6] = Wo;    ca.dst[6] = Wob; ca.n8[6] = (int)(NW / 8);

  cvt_bf16<<<dim3((unsigned)(NE / 8 / 256), 1, 7), dim3(256), 0, stream>>>(ca);
  proj_qkv<<<dim3(768), dim3(256), 0, stream>>>(
      Xq, Xk, Xv, Wqb, Wkb, Wvb, Q, K, Vt);
  flash_attn<<<dim3(NT * BATCH * HEADS), dim3(512), 0, stream>>>(Q, K, Vt, A);
  proj_out<<<dim3(512), dim3(256), 0, stream>>>(A, Wob, (float*)d_out);
}